// Round 5
// baseline (404.140 us; speedup 1.0000x reference)
//
#include <hip/hip_runtime.h>
#include <math.h>

#define N_NODES 100000
#define N_EDGES 1600000
#define IN_F 128
#define H_F 64
#define KP 68        // padded LDS leading dim for A tiles

#define NBKT 196     // ceil(100000/512) buckets of 512 nodes
#define BSEG 16384   // per-bucket segment capacity
#define BCAP 14336   // LDS staging capacity for adj per bucket (56KB)

// workspace layout in 4-byte words
#define NP        100096
#define OFF_CNT   0                           // int[256]
#define OFF_BBASE 256                         // int[256]
#define OFF_OFFS  512                         // int[N+1] (NP+64)
#define OFF_D2    (512 + NP + 64)             // float[NP]
#define OFF_RD    (OFF_D2 + NP)               // float[NP]
#define OFF_DINV  (OFF_RD + NP)               // float[NP]
#define OFF_ADJ   (OFF_DINV + NP)             // int[N_EDGES]
#define OFF_BUFA  (OFF_ADJ + N_EDGES)         // binned only (gs2 never materialized)
#define OFF_BUFB  (OFF_BUFA + N_NODES*H_F)    // float[N*64]  gs0
#define OFF_BUFC  (OFF_BUFB + N_NODES*H_F)    // float[N*64]  gs1

// ---- pass A: bin edges by dst>>9, packed (local<<17 | src) ----
__global__ __launch_bounds__(256) void k_bin(const int* __restrict__ src,
        const int* __restrict__ dst, int* __restrict__ cnt,
        int* __restrict__ binned, int E) {
    __shared__ int hist[NBKT];
    __shared__ int curb[NBKT];
    int t = threadIdx.x;
    for (int i = t; i < NBKT; i += 256) hist[i] = 0;
    __syncthreads();
    int base = blockIdx.x * 4096 + t;
    int d[16];
    #pragma unroll
    for (int i = 0; i < 16; ++i) {
        int e = base + i * 256;
        int dd = (e < E) ? dst[e] : -1;
        d[i] = dd;
        if (dd >= 0) atomicAdd(&hist[dd >> 9], 1);
    }
    __syncthreads();
    for (int i = t; i < NBKT; i += 256) {
        int h = hist[i];
        curb[i] = (h > 0) ? atomicAdd(&cnt[i], h) : 0;
    }
    __syncthreads();
    #pragma unroll
    for (int i = 0; i < 16; ++i) {
        int e = base + i * 256;
        if (e < E) {
            int s = src[e];
            int dd = d[i];
            int b = dd >> 9;
            int p = atomicAdd(&curb[b], 1);
            if (p < BSEG) binned[b * BSEG + p] = ((dd & 511) << 17) | s;
        }
    }
}

// ---- pass B: exclusive scan of bucket counts ----
__global__ __launch_bounds__(256) void k_bscan(const int* __restrict__ cnt,
        int* __restrict__ bbase, int* __restrict__ offs) {
    __shared__ int sm[256];
    int t = threadIdx.x;
    int v = (t < NBKT) ? cnt[t] : 0;
    sm[t] = v;
    __syncthreads();
    #pragma unroll
    for (int off = 1; off < 256; off <<= 1) {
        int u = (t >= off) ? sm[t - off] : 0;
        __syncthreads();
        sm[t] += u;
        __syncthreads();
    }
    if (t < NBKT) bbase[t] = sm[t] - v;
    if (t == 0) offs[N_NODES] = N_EDGES;
}

// ---- pass C: per-bucket CSR fill with LDS staging + degree-derived arrays ----
__global__ __launch_bounds__(256) void k_cfill(const int* __restrict__ binned,
        const int* __restrict__ cnt, const int* __restrict__ bbase,
        int* __restrict__ offs, int* __restrict__ adj,
        float* __restrict__ d2a, float* __restrict__ rda, float* __restrict__ dinva) {
    __shared__ int degl[512];
    __shared__ int offl[512];
    __shared__ int curl[512];
    __shared__ int wsum[4];
    __shared__ int adjl[BCAP];
    int b = blockIdx.x, t = threadIdx.x;
    int n0 = b << 9;
    int cntb = cnt[b];
    int baseb = bbase[b];
    const int* bp = binned + b * BSEG;
    degl[2 * t] = 0; degl[2 * t + 1] = 0;
    __syncthreads();
    for (int i = t; i < cntb; i += 256) {
        int w = bp[i];
        atomicAdd(&degl[w >> 17], 1);
    }
    __syncthreads();
    int d0 = degl[2 * t], d1 = degl[2 * t + 1];
    int tot = d0 + d1;
    int lane = t & 63, wid = t >> 6;
    int inc = tot;
    #pragma unroll
    for (int off = 1; off < 64; off <<= 1) {
        int v = __shfl_up(inc, off, 64);
        if (lane >= off) inc += v;
    }
    if (lane == 63) wsum[wid] = inc;
    __syncthreads();
    int wb = 0;
    for (int w = 0; w < wid; ++w) wb += wsum[w];
    int excl = wb + inc - tot;
    offl[2 * t] = excl;       curl[2 * t] = excl;
    offl[2 * t + 1] = excl + d0; curl[2 * t + 1] = excl + d0;
    __syncthreads();
    #pragma unroll
    for (int rep = 0; rep < 2; ++rep) {
        int i = t + rep * 256;
        int n = n0 + i;
        if (n < N_NODES) {
            offs[n] = baseb + offl[i];
            float df = (float)degl[i];
            if (df < 1.f) df = 1.f;
            float di = 1.0f / sqrtf(df);
            dinva[n] = di;
            d2a[n] = di * di;
            rda[n] = sqrtf(df);
        }
    }
    for (int i = t; i < cntb; i += 256) {
        int w = bp[i];
        int loc = w >> 17;
        int s = w & 0x1FFFF;
        int p = atomicAdd(&curl[loc], 1);
        if (p < BCAP) adjl[p] = s;
        else adj[baseb + p] = s;
    }
    __syncthreads();
    int lim = cntb < BCAP ? cntb : BCAP;
    for (int i = t; i < lim; i += 256) adj[baseb + i] = adjl[i];
}

// ======= fused MLP: gs0 = dinv .* relu(relu(x@W1+b1)@W2+b2), 64-node tiles ==
__global__ __launch_bounds__(256) void k_gemm12(const float* __restrict__ x,
        const float* __restrict__ W1, const float* __restrict__ b1,
        const float* __restrict__ W2, const float* __restrict__ b2,
        const float* __restrict__ dinva, float* __restrict__ gs, int N) {
    __shared__ float Al[64 * KP];
    __shared__ float Bl[64 * 64];
    __shared__ float Hl[64 * KP];
    int t = threadIdx.x;
    int tx = t & 15, ty = t >> 4;
    int nb = blockIdx.x * 64;
    float acc[4][4] = {{0}};
    // ---- GEMM1: K=128 in 2 phases ----
    for (int p = 0; p < 2; ++p) {
        #pragma unroll
        for (int pp = 0; pp < 4; ++pp) {
            int nl = ty + 16 * pp;
            int nn = nb + nl; if (nn >= N) nn = N - 1;
            float4 v = ((const float4*)(x + (size_t)nn * IN_F + p * 64))[tx];
            *(float4*)&Al[nl * KP + 4 * tx] = v;
        }
        #pragma unroll
        for (int pp = 0; pp < 4; ++pp) {
            int k = ty + 16 * pp;
            float4 v = ((const float4*)(W1 + (size_t)(p * 64 + k) * 64))[tx];
            *(float4*)&Bl[k * 64 + 4 * tx] = v;
        }
        __syncthreads();
        #pragma unroll 4
        for (int k = 0; k < 64; ++k) {
            float a0 = Al[(4 * ty + 0) * KP + k];
            float a1 = Al[(4 * ty + 1) * KP + k];
            float a2 = Al[(4 * ty + 2) * KP + k];
            float a3 = Al[(4 * ty + 3) * KP + k];
            float4 bv = *(const float4*)&Bl[k * 64 + 4 * tx];
            acc[0][0] = fmaf(a0, bv.x, acc[0][0]); acc[0][1] = fmaf(a0, bv.y, acc[0][1]);
            acc[0][2] = fmaf(a0, bv.z, acc[0][2]); acc[0][3] = fmaf(a0, bv.w, acc[0][3]);
            acc[1][0] = fmaf(a1, bv.x, acc[1][0]); acc[1][1] = fmaf(a1, bv.y, acc[1][1]);
            acc[1][2] = fmaf(a1, bv.z, acc[1][2]); acc[1][3] = fmaf(a1, bv.w, acc[1][3]);
            acc[2][0] = fmaf(a2, bv.x, acc[2][0]); acc[2][1] = fmaf(a2, bv.y, acc[2][1]);
            acc[2][2] = fmaf(a2, bv.z, acc[2][2]); acc[2][3] = fmaf(a2, bv.w, acc[2][3]);
            acc[3][0] = fmaf(a3, bv.x, acc[3][0]); acc[3][1] = fmaf(a3, bv.y, acc[3][1]);
            acc[3][2] = fmaf(a3, bv.z, acc[3][2]); acc[3][3] = fmaf(a3, bv.w, acc[3][3]);
        }
        __syncthreads();
    }
    // ---- h1 = relu(acc + b1) -> Hl; load W2 -> Bl ----
    {
        float4 bias = ((const float4*)b1)[tx];
        #pragma unroll
        for (int i = 0; i < 4; ++i) {
            float4 r;
            r.x = fmaxf(acc[i][0] + bias.x, 0.f);
            r.y = fmaxf(acc[i][1] + bias.y, 0.f);
            r.z = fmaxf(acc[i][2] + bias.z, 0.f);
            r.w = fmaxf(acc[i][3] + bias.w, 0.f);
            *(float4*)&Hl[(4 * ty + i) * KP + 4 * tx] = r;
            acc[i][0] = 0.f; acc[i][1] = 0.f; acc[i][2] = 0.f; acc[i][3] = 0.f;
        }
        #pragma unroll
        for (int pp = 0; pp < 4; ++pp) {
            int k = ty + 16 * pp;
            float4 v = ((const float4*)(W2 + (size_t)k * 64))[tx];
            *(float4*)&Bl[k * 64 + 4 * tx] = v;
        }
    }
    __syncthreads();
    // ---- GEMM2: K=64 from Hl ----
    #pragma unroll 4
    for (int k = 0; k < 64; ++k) {
        float a0 = Hl[(4 * ty + 0) * KP + k];
        float a1 = Hl[(4 * ty + 1) * KP + k];
        float a2 = Hl[(4 * ty + 2) * KP + k];
        float a3 = Hl[(4 * ty + 3) * KP + k];
        float4 bv = *(const float4*)&Bl[k * 64 + 4 * tx];
        acc[0][0] = fmaf(a0, bv.x, acc[0][0]); acc[0][1] = fmaf(a0, bv.y, acc[0][1]);
        acc[0][2] = fmaf(a0, bv.z, acc[0][2]); acc[0][3] = fmaf(a0, bv.w, acc[0][3]);
        acc[1][0] = fmaf(a1, bv.x, acc[1][0]); acc[1][1] = fmaf(a1, bv.y, acc[1][1]);
        acc[1][2] = fmaf(a1, bv.z, acc[1][2]); acc[1][3] = fmaf(a1, bv.w, acc[1][3]);
        acc[2][0] = fmaf(a2, bv.x, acc[2][0]); acc[2][1] = fmaf(a2, bv.y, acc[2][1]);
        acc[2][2] = fmaf(a2, bv.z, acc[2][2]); acc[2][3] = fmaf(a2, bv.w, acc[2][3]);
        acc[3][0] = fmaf(a3, bv.x, acc[3][0]); acc[3][1] = fmaf(a3, bv.y, acc[3][1]);
        acc[3][2] = fmaf(a3, bv.z, acc[3][2]); acc[3][3] = fmaf(a3, bv.w, acc[3][3]);
    }
    float4 bias2 = ((const float4*)b2)[tx];
    #pragma unroll
    for (int i = 0; i < 4; ++i) {
        int n = nb + 4 * ty + i;
        if (n < N) {
            float di = dinva[n];
            float4 r;
            r.x = di * fmaxf(acc[i][0] + bias2.x, 0.f);
            r.y = di * fmaxf(acc[i][1] + bias2.y, 0.f);
            r.z = di * fmaxf(acc[i][2] + bias2.z, 0.f);
            r.w = di * fmaxf(acc[i][3] + bias2.w, 0.f);
            ((float4*)(gs + (size_t)n * 64))[tx] = r;
        }
    }
}

// ---- propagation 1: gs1 = gs0 - d2[n] * sum_src gs0[src] ----
__global__ __launch_bounds__(256) void k_prop(const float* __restrict__ gs,
        float* __restrict__ gsn, const int* __restrict__ offs,
        const int* __restrict__ adj, const float* __restrict__ d2a, int N) {
    int t = threadIdx.x;
    int lane = t & 63;
    int g = lane >> 4;
    int q = lane & 15;
    int n = blockIdx.x * 4 + (t >> 6);
    if (n >= N) return;
    int beg = offs[n], end = offs[n + 1];
    const float4* gs4 = (const float4*)gs;
    float ax = 0.f, ay = 0.f, az = 0.f, aw = 0.f;
    int e = beg + g;
    for (; e + 12 < end; e += 16) {
        int s0 = adj[e], s1 = adj[e + 4], s2 = adj[e + 8], s3 = adj[e + 12];
        float4 f0 = gs4[(size_t)s0 * 16 + q];
        float4 f1 = gs4[(size_t)s1 * 16 + q];
        float4 f2 = gs4[(size_t)s2 * 16 + q];
        float4 f3 = gs4[(size_t)s3 * 16 + q];
        ax += (f0.x + f1.x) + (f2.x + f3.x);
        ay += (f0.y + f1.y) + (f2.y + f3.y);
        az += (f0.z + f1.z) + (f2.z + f3.z);
        aw += (f0.w + f1.w) + (f2.w + f3.w);
    }
    for (; e < end; e += 4) {
        int s = adj[e];
        float4 f = gs4[(size_t)s * 16 + q];
        ax += f.x; ay += f.y; az += f.z; aw += f.w;
    }
    ax += __shfl_xor(ax, 16); ay += __shfl_xor(ay, 16);
    az += __shfl_xor(az, 16); aw += __shfl_xor(aw, 16);
    ax += __shfl_xor(ax, 32); ay += __shfl_xor(ay, 32);
    az += __shfl_xor(az, 32); aw += __shfl_xor(aw, 32);
    if (g == 0) {
        float d2n = d2a[n];
        float4 self = gs4[(size_t)n * 16 + q];
        float4 r;
        r.x = fmaf(-d2n, ax, self.x);
        r.y = fmaf(-d2n, ay, self.y);
        r.z = fmaf(-d2n, az, self.z);
        r.w = fmaf(-d2n, aw, self.w);
        ((float4*)gsn)[(size_t)n * 16 + q] = r;
    }
}

// ===== fused prop2+final: gs2 rows gathered straight into LDS, then head ====
__global__ __launch_bounds__(256) void k_prop_final(const float* __restrict__ gs0,
        const float* __restrict__ gs1, const int* __restrict__ offs,
        const int* __restrict__ adj, const float* __restrict__ d2a,
        const float* __restrict__ Wm1, const float* __restrict__ bm1,
        const float* __restrict__ Wm2, const float* __restrict__ bm2,
        const float* __restrict__ rda, float* __restrict__ out, int N) {
    __shared__ float G2[64 * KP];
    __shared__ float Al[64 * KP];
    __shared__ float Bl[64 * 64];
    int t = threadIdx.x;
    int lane = t & 63;
    int w = t >> 6;
    int g = lane >> 4;
    int q = lane & 15;
    int nb = blockIdx.x * 64;
    const float4* gs1v = (const float4*)gs1;
    // ---- phase 1: wave w gathers gs2 rows for nodes nb+16w .. nb+16w+15 ----
    for (int i = 0; i < 16; ++i) {
        int nl = w * 16 + i;
        int n = nb + nl;
        float ax = 0.f, ay = 0.f, az = 0.f, aw = 0.f;
        if (n < N) {
            int beg = offs[n], end = offs[n + 1];
            int e = beg + g;
            for (; e + 12 < end; e += 16) {
                int s0 = adj[e], s1 = adj[e + 4], s2 = adj[e + 8], s3 = adj[e + 12];
                float4 f0 = gs1v[(size_t)s0 * 16 + q];
                float4 f1 = gs1v[(size_t)s1 * 16 + q];
                float4 f2 = gs1v[(size_t)s2 * 16 + q];
                float4 f3 = gs1v[(size_t)s3 * 16 + q];
                ax += (f0.x + f1.x) + (f2.x + f3.x);
                ay += (f0.y + f1.y) + (f2.y + f3.y);
                az += (f0.z + f1.z) + (f2.z + f3.z);
                aw += (f0.w + f1.w) + (f2.w + f3.w);
            }
            for (; e < end; e += 4) {
                int s = adj[e];
                float4 f = gs1v[(size_t)s * 16 + q];
                ax += f.x; ay += f.y; az += f.z; aw += f.w;
            }
        }
        ax += __shfl_xor(ax, 16); ay += __shfl_xor(ay, 16);
        az += __shfl_xor(az, 16); aw += __shfl_xor(aw, 16);
        ax += __shfl_xor(ax, 32); ay += __shfl_xor(ay, 32);
        az += __shfl_xor(az, 32); aw += __shfl_xor(aw, 32);
        if (g == 0) {
            float4 r = {0.f, 0.f, 0.f, 0.f};
            if (n < N) {
                float d2n = d2a[n];
                float4 self = gs1v[(size_t)n * 16 + q];
                r.x = fmaf(-d2n, ax, self.x);
                r.y = fmaf(-d2n, ay, self.y);
                r.z = fmaf(-d2n, az, self.z);
                r.w = fmaf(-d2n, aw, self.w);
            }
            *(float4*)&G2[nl * KP + 4 * q] = r;
        }
    }
    __syncthreads();
    // ---- phase 2: head GEMM over 3 K-slices ----
    int tx = t & 15, ty = t >> 4;
    float acc[4][4] = {{0}};
    for (int p = 0; p < 3; ++p) {
        if (p < 2) {
            const float* gp = (p == 0) ? gs0 : gs1;
            #pragma unroll
            for (int pp = 0; pp < 4; ++pp) {
                int nl = ty + 16 * pp;
                int nn = nb + nl; if (nn >= N) nn = N - 1;
                float4 v = ((const float4*)(gp + (size_t)nn * 64))[tx];
                *(float4*)&Al[nl * KP + 4 * tx] = v;
            }
        }
        #pragma unroll
        for (int pp = 0; pp < 4; ++pp) {
            int k = ty + 16 * pp;
            float4 w0 = ((const float4*)(Wm1 + (size_t)k * 64))[tx];
            float4 w1 = ((const float4*)(Wm1 + (size_t)(64 + k) * 64))[tx];
            float4 w2 = ((const float4*)(Wm1 + (size_t)(128 + k) * 64))[tx];
            float4 mv;
            if (p == 0) {
                mv.x = 3.0f * w0.x; mv.y = 3.0f * w0.y;
                mv.z = 3.0f * w0.z; mv.w = 3.0f * w0.w;
            } else if (p == 1) {
                mv.x = fmaf(-3.0f, w0.x, 3.0f * w1.x);
                mv.y = fmaf(-3.0f, w0.y, 3.0f * w1.y);
                mv.z = fmaf(-3.0f, w0.z, 3.0f * w1.z);
                mv.w = fmaf(-3.0f, w0.w, 3.0f * w1.w);
            } else {
                mv.x = 0.75f * (w0.x + w2.x) - 1.5f * w1.x;
                mv.y = 0.75f * (w0.y + w2.y) - 1.5f * w1.y;
                mv.z = 0.75f * (w0.z + w2.z) - 1.5f * w1.z;
                mv.w = 0.75f * (w0.w + w2.w) - 1.5f * w1.w;
            }
            *(float4*)&Bl[k * 64 + 4 * tx] = mv;
        }
        __syncthreads();
        const float* Ap = (p == 2) ? G2 : Al;
        #pragma unroll 4
        for (int k = 0; k < 64; ++k) {
            float a0 = Ap[(4 * ty + 0) * KP + k];
            float a1 = Ap[(4 * ty + 1) * KP + k];
            float a2 = Ap[(4 * ty + 2) * KP + k];
            float a3 = Ap[(4 * ty + 3) * KP + k];
            float4 bv = *(const float4*)&Bl[k * 64 + 4 * tx];
            acc[0][0] = fmaf(a0, bv.x, acc[0][0]); acc[0][1] = fmaf(a0, bv.y, acc[0][1]);
            acc[0][2] = fmaf(a0, bv.z, acc[0][2]); acc[0][3] = fmaf(a0, bv.w, acc[0][3]);
            acc[1][0] = fmaf(a1, bv.x, acc[1][0]); acc[1][1] = fmaf(a1, bv.y, acc[1][1]);
            acc[1][2] = fmaf(a1, bv.z, acc[1][2]); acc[1][3] = fmaf(a1, bv.w, acc[1][3]);
            acc[2][0] = fmaf(a2, bv.x, acc[2][0]); acc[2][1] = fmaf(a2, bv.y, acc[2][1]);
            acc[2][2] = fmaf(a2, bv.z, acc[2][2]); acc[2][3] = fmaf(a2, bv.w, acc[2][3]);
            acc[3][0] = fmaf(a3, bv.x, acc[3][0]); acc[3][1] = fmaf(a3, bv.y, acc[3][1]);
            acc[3][2] = fmaf(a3, bv.z, acc[3][2]); acc[3][3] = fmaf(a3, bv.w, acc[3][3]);
        }
        __syncthreads();
    }
    float4 bmv = ((const float4*)bm1)[tx];
    float4 wa = ((const float4*)Wm2)[2 * tx];
    float4 wb = ((const float4*)Wm2)[2 * tx + 1];
    float bo0 = bm2[0], bo1 = bm2[1];
    #pragma unroll
    for (int i = 0; i < 4; ++i) {
        int n = nb + 4 * ty + i;
        float rdn = rda[(n < N) ? n : (N - 1)];
        float h0 = fmaxf(fmaf(rdn, acc[i][0], bmv.x), 0.f);
        float h1 = fmaxf(fmaf(rdn, acc[i][1], bmv.y), 0.f);
        float h2 = fmaxf(fmaf(rdn, acc[i][2], bmv.z), 0.f);
        float h3 = fmaxf(fmaf(rdn, acc[i][3], bmv.w), 0.f);
        float p0 = h0 * wa.x + h1 * wa.z + h2 * wb.x + h3 * wb.z;
        float p1 = h0 * wa.y + h1 * wa.w + h2 * wb.y + h3 * wb.w;
        #pragma unroll
        for (int m = 1; m < 16; m <<= 1) {
            p0 += __shfl_xor(p0, m);
            p1 += __shfl_xor(p1, m);
        }
        if (tx == 0 && n < N) {
            out[(size_t)n * 2 + 0] = p0 + bo0;
            out[(size_t)n * 2 + 1] = p1 + bo1;
        }
    }
}

extern "C" void kernel_launch(void* const* d_in, const int* in_sizes, int n_in,
                              void* d_out, int out_size, void* d_ws, size_t ws_size,
                              hipStream_t stream) {
    const float* x   = (const float*)d_in[0];
    const int*   ei  = (const int*)d_in[1];
    const float* W1  = (const float*)d_in[2];
    const float* b1  = (const float*)d_in[3];
    const float* W2  = (const float*)d_in[4];
    const float* b2  = (const float*)d_in[5];
    const float* Wm1 = (const float*)d_in[6];
    const float* bm1 = (const float*)d_in[7];
    const float* Wm2 = (const float*)d_in[8];
    const float* bm2 = (const float*)d_in[9];
    float* out = (float*)d_out;

    int* ws = (int*)d_ws;
    int*   cnt   = ws + OFF_CNT;
    int*   bbase = ws + OFF_BBASE;
    int*   offs  = ws + OFF_OFFS;
    float* d2a   = (float*)(ws + OFF_D2);
    float* rda   = (float*)(ws + OFF_RD);
    float* dinva = (float*)(ws + OFF_DINV);
    int*   adj   = ws + OFF_ADJ;
    int*   binned = ws + OFF_BUFA;            // aliases bufA region (dead after cfill)
    float* bufB  = (float*)(ws + OFF_BUFB);   // gs0
    float* bufC  = (float*)(ws + OFF_BUFC);   // gs1

    const int* srcp = ei;
    const int* dstp = ei + N_EDGES;

    hipMemsetAsync(cnt, 0, 256 * sizeof(int), stream);

    k_bin<<<(N_EDGES + 4095) / 4096, 256, 0, stream>>>(srcp, dstp, cnt, binned, N_EDGES);
    k_bscan<<<1, 256, 0, stream>>>(cnt, bbase, offs);
    k_cfill<<<NBKT, 256, 0, stream>>>(binned, cnt, bbase, offs, adj, d2a, rda, dinva);

    int nblk = (N_NODES + 63) / 64;
    k_gemm12<<<nblk, 256, 0, stream>>>(x, W1, b1, W2, b2, dinva, bufB, N_NODES);  // gs0

    k_prop<<<(N_NODES + 3) / 4, 256, 0, stream>>>(bufB, bufC, offs, adj, d2a, N_NODES); // gs1

    k_prop_final<<<nblk, 256, 0, stream>>>(bufB, bufC, offs, adj, d2a,
                                           Wm1, bm1, Wm2, bm2, rda, out, N_NODES);
}

// Round 6
// 322.293 us; speedup vs baseline: 1.2540x; 1.2540x over previous
//
#include <hip/hip_runtime.h>
#include <math.h>

#define N_NODES 100000
#define N_EDGES 1600000
#define IN_F 128
#define H_F 64
#define KP 68        // padded LDS leading dim for A tiles

#define NBKT 196     // ceil(100000/512) buckets of 512 nodes
#define BSEG 16384   // per-bucket segment capacity
#define BCAP 14336   // LDS staging capacity for adj per bucket (56KB)

// workspace layout in 4-byte words (total ~21.2M words = 85 MB)
#define NP        100096
#define OFF_CNT   0                           // int[256] cnt
#define OFF_BBASE 256                         // int[256]
#define OFF_OFFS  512                         // int[N+1]
#define OFF_D2    (512 + NP + 64)             // float[NP]
#define OFF_RD    (OFF_D2 + NP)               // float[NP]
#define OFF_DINV  (OFF_RD + NP)               // float[NP]
#define OFF_ADJ   (OFF_DINV + NP)             // int[N_EDGES]
#define OFF_H0    (OFF_ADJ + N_EDGES)         // ushort[N*64] bf16 gs0 (3.2M words)
#define OFF_H1    (OFF_H0 + N_NODES*H_F/2)    // ushort[N*64] bf16 gs1 (3.2M words)
#define OFF_BUFA  (OFF_H1 + N_NODES*H_F/2)    // binned alias, then float gs2 [N*64]
#define OFF_BUFB  (OFF_BUFA + N_NODES*H_F)    // float[N*64] gs0 fp32

__device__ __forceinline__ unsigned short bf16rn(float f) {
    unsigned u = __float_as_uint(f);
    u += 0x7FFFu + ((u >> 16) & 1u);
    return (unsigned short)(u >> 16);
}
__device__ __forceinline__ float4 bf4tof(ushort4 h) {
    float4 f;
    f.x = __uint_as_float((unsigned)h.x << 16);
    f.y = __uint_as_float((unsigned)h.y << 16);
    f.z = __uint_as_float((unsigned)h.z << 16);
    f.w = __uint_as_float((unsigned)h.w << 16);
    return f;
}

// ---- pass A: bin edges by dst>>9, packed (local<<17 | src) ----
__global__ __launch_bounds__(256) void k_bin(const int* __restrict__ src,
        const int* __restrict__ dst, int* __restrict__ cnt,
        int* __restrict__ binned, int E) {
    __shared__ int hist[NBKT];
    __shared__ int curb[NBKT];
    int t = threadIdx.x;
    for (int i = t; i < NBKT; i += 256) hist[i] = 0;
    __syncthreads();
    int base = blockIdx.x * 4096 + t;
    int d[16];
    #pragma unroll
    for (int i = 0; i < 16; ++i) {
        int e = base + i * 256;
        int dd = (e < E) ? dst[e] : -1;
        d[i] = dd;
        if (dd >= 0) atomicAdd(&hist[dd >> 9], 1);
    }
    __syncthreads();
    for (int i = t; i < NBKT; i += 256) {
        int h = hist[i];
        curb[i] = (h > 0) ? atomicAdd(&cnt[i], h) : 0;
    }
    __syncthreads();
    #pragma unroll
    for (int i = 0; i < 16; ++i) {
        int e = base + i * 256;
        if (e < E) {
            int s = src[e];
            int dd = d[i];
            int b = dd >> 9;
            int p = atomicAdd(&curb[b], 1);
            if (p < BSEG) binned[b * BSEG + p] = ((dd & 511) << 17) | s;
        }
    }
}

// ---- pass B: exclusive scan of bucket counts ----
__global__ __launch_bounds__(256) void k_bscan(const int* __restrict__ cnt,
        int* __restrict__ bbase, int* __restrict__ offs) {
    __shared__ int sm[256];
    int t = threadIdx.x;
    int v = (t < NBKT) ? cnt[t] : 0;
    sm[t] = v;
    __syncthreads();
    #pragma unroll
    for (int off = 1; off < 256; off <<= 1) {
        int u = (t >= off) ? sm[t - off] : 0;
        __syncthreads();
        sm[t] += u;
        __syncthreads();
    }
    if (t < NBKT) bbase[t] = sm[t] - v;
    if (t == 0) offs[N_NODES] = N_EDGES;
}

// ---- pass C: per-bucket CSR fill with LDS staging + degree-derived arrays ----
__global__ __launch_bounds__(256) void k_cfill(const int* __restrict__ binned,
        const int* __restrict__ cnt, const int* __restrict__ bbase,
        int* __restrict__ offs, int* __restrict__ adj,
        float* __restrict__ d2a, float* __restrict__ rda, float* __restrict__ dinva) {
    __shared__ int degl[512];
    __shared__ int offl[512];
    __shared__ int curl[512];
    __shared__ int wsum[4];
    __shared__ int adjl[BCAP];
    int b = blockIdx.x, t = threadIdx.x;
    int n0 = b << 9;
    int cntb = cnt[b];
    int baseb = bbase[b];
    const int* bp = binned + b * BSEG;
    degl[2 * t] = 0; degl[2 * t + 1] = 0;
    __syncthreads();
    for (int i = t; i < cntb; i += 256) {
        int w = bp[i];
        atomicAdd(&degl[w >> 17], 1);
    }
    __syncthreads();
    int d0 = degl[2 * t], d1 = degl[2 * t + 1];
    int tot = d0 + d1;
    int lane = t & 63, wid = t >> 6;
    int inc = tot;
    #pragma unroll
    for (int off = 1; off < 64; off <<= 1) {
        int v = __shfl_up(inc, off, 64);
        if (lane >= off) inc += v;
    }
    if (lane == 63) wsum[wid] = inc;
    __syncthreads();
    int wb = 0;
    for (int w = 0; w < wid; ++w) wb += wsum[w];
    int excl = wb + inc - tot;
    offl[2 * t] = excl;       curl[2 * t] = excl;
    offl[2 * t + 1] = excl + d0; curl[2 * t + 1] = excl + d0;
    __syncthreads();
    #pragma unroll
    for (int rep = 0; rep < 2; ++rep) {
        int i = t + rep * 256;
        int n = n0 + i;
        if (n < N_NODES) {
            offs[n] = baseb + offl[i];
            float df = (float)degl[i];
            if (df < 1.f) df = 1.f;
            float di = 1.0f / sqrtf(df);
            dinva[n] = di;
            d2a[n] = di * di;
            rda[n] = sqrtf(df);
        }
    }
    for (int i = t; i < cntb; i += 256) {
        int w = bp[i];
        int loc = w >> 17;
        int s = w & 0x1FFFF;
        int p = atomicAdd(&curl[loc], 1);
        if (p < BCAP) adjl[p] = s;
        else adj[baseb + p] = s;
    }
    __syncthreads();
    int lim = cntb < BCAP ? cntb : BCAP;
    for (int i = t; i < lim; i += 256) adj[baseb + i] = adjl[i];
}

// ======= fused MLP: gs0 = dinv .* relu(relu(x@W1+b1)@W2+b2) =================
// writes fp32 master + bf16 shadow (for gathers)
__global__ __launch_bounds__(256) void k_gemm12(const float* __restrict__ x,
        const float* __restrict__ W1, const float* __restrict__ b1,
        const float* __restrict__ W2, const float* __restrict__ b2,
        const float* __restrict__ dinva, float* __restrict__ gs,
        unsigned short* __restrict__ gsh, int N) {
    __shared__ float Al[64 * KP];
    __shared__ float Bl[64 * 64];
    __shared__ float Hl[64 * KP];
    int t = threadIdx.x;
    int tx = t & 15, ty = t >> 4;
    int nb = blockIdx.x * 64;
    float acc[4][4] = {{0}};
    for (int p = 0; p < 2; ++p) {
        #pragma unroll
        for (int pp = 0; pp < 4; ++pp) {
            int nl = ty + 16 * pp;
            int nn = nb + nl; if (nn >= N) nn = N - 1;
            float4 v = ((const float4*)(x + (size_t)nn * IN_F + p * 64))[tx];
            *(float4*)&Al[nl * KP + 4 * tx] = v;
        }
        #pragma unroll
        for (int pp = 0; pp < 4; ++pp) {
            int k = ty + 16 * pp;
            float4 v = ((const float4*)(W1 + (size_t)(p * 64 + k) * 64))[tx];
            *(float4*)&Bl[k * 64 + 4 * tx] = v;
        }
        __syncthreads();
        #pragma unroll 4
        for (int k = 0; k < 64; ++k) {
            float a0 = Al[(4 * ty + 0) * KP + k];
            float a1 = Al[(4 * ty + 1) * KP + k];
            float a2 = Al[(4 * ty + 2) * KP + k];
            float a3 = Al[(4 * ty + 3) * KP + k];
            float4 bv = *(const float4*)&Bl[k * 64 + 4 * tx];
            acc[0][0] = fmaf(a0, bv.x, acc[0][0]); acc[0][1] = fmaf(a0, bv.y, acc[0][1]);
            acc[0][2] = fmaf(a0, bv.z, acc[0][2]); acc[0][3] = fmaf(a0, bv.w, acc[0][3]);
            acc[1][0] = fmaf(a1, bv.x, acc[1][0]); acc[1][1] = fmaf(a1, bv.y, acc[1][1]);
            acc[1][2] = fmaf(a1, bv.z, acc[1][2]); acc[1][3] = fmaf(a1, bv.w, acc[1][3]);
            acc[2][0] = fmaf(a2, bv.x, acc[2][0]); acc[2][1] = fmaf(a2, bv.y, acc[2][1]);
            acc[2][2] = fmaf(a2, bv.z, acc[2][2]); acc[2][3] = fmaf(a2, bv.w, acc[2][3]);
            acc[3][0] = fmaf(a3, bv.x, acc[3][0]); acc[3][1] = fmaf(a3, bv.y, acc[3][1]);
            acc[3][2] = fmaf(a3, bv.z, acc[3][2]); acc[3][3] = fmaf(a3, bv.w, acc[3][3]);
        }
        __syncthreads();
    }
    {
        float4 bias = ((const float4*)b1)[tx];
        #pragma unroll
        for (int i = 0; i < 4; ++i) {
            float4 r;
            r.x = fmaxf(acc[i][0] + bias.x, 0.f);
            r.y = fmaxf(acc[i][1] + bias.y, 0.f);
            r.z = fmaxf(acc[i][2] + bias.z, 0.f);
            r.w = fmaxf(acc[i][3] + bias.w, 0.f);
            *(float4*)&Hl[(4 * ty + i) * KP + 4 * tx] = r;
            acc[i][0] = 0.f; acc[i][1] = 0.f; acc[i][2] = 0.f; acc[i][3] = 0.f;
        }
        #pragma unroll
        for (int pp = 0; pp < 4; ++pp) {
            int k = ty + 16 * pp;
            float4 v = ((const float4*)(W2 + (size_t)k * 64))[tx];
            *(float4*)&Bl[k * 64 + 4 * tx] = v;
        }
    }
    __syncthreads();
    #pragma unroll 4
    for (int k = 0; k < 64; ++k) {
        float a0 = Hl[(4 * ty + 0) * KP + k];
        float a1 = Hl[(4 * ty + 1) * KP + k];
        float a2 = Hl[(4 * ty + 2) * KP + k];
        float a3 = Hl[(4 * ty + 3) * KP + k];
        float4 bv = *(const float4*)&Bl[k * 64 + 4 * tx];
        acc[0][0] = fmaf(a0, bv.x, acc[0][0]); acc[0][1] = fmaf(a0, bv.y, acc[0][1]);
        acc[0][2] = fmaf(a0, bv.z, acc[0][2]); acc[0][3] = fmaf(a0, bv.w, acc[0][3]);
        acc[1][0] = fmaf(a1, bv.x, acc[1][0]); acc[1][1] = fmaf(a1, bv.y, acc[1][1]);
        acc[1][2] = fmaf(a1, bv.z, acc[1][2]); acc[1][3] = fmaf(a1, bv.w, acc[1][3]);
        acc[2][0] = fmaf(a2, bv.x, acc[2][0]); acc[2][1] = fmaf(a2, bv.y, acc[2][1]);
        acc[2][2] = fmaf(a2, bv.z, acc[2][2]); acc[2][3] = fmaf(a2, bv.w, acc[2][3]);
        acc[3][0] = fmaf(a3, bv.x, acc[3][0]); acc[3][1] = fmaf(a3, bv.y, acc[3][1]);
        acc[3][2] = fmaf(a3, bv.z, acc[3][2]); acc[3][3] = fmaf(a3, bv.w, acc[3][3]);
    }
    float4 bias2 = ((const float4*)b2)[tx];
    #pragma unroll
    for (int i = 0; i < 4; ++i) {
        int n = nb + 4 * ty + i;
        if (n < N) {
            float di = dinva[n];
            float4 r;
            r.x = di * fmaxf(acc[i][0] + bias2.x, 0.f);
            r.y = di * fmaxf(acc[i][1] + bias2.y, 0.f);
            r.z = di * fmaxf(acc[i][2] + bias2.z, 0.f);
            r.w = di * fmaxf(acc[i][3] + bias2.w, 0.f);
            ((float4*)(gs + (size_t)n * 64))[tx] = r;
            ushort4 hh;
            hh.x = bf16rn(r.x); hh.y = bf16rn(r.y);
            hh.z = bf16rn(r.z); hh.w = bf16rn(r.w);
            *(ushort4*)(gsh + (size_t)n * 64 + 4 * tx) = hh;
        }
    }
}

// ---- prop1: gs1h = bf16(gs0 - d2[n] * sum_src bf16(gs0)[src]) ----
// gather from bf16 shadow (128B rows), self from fp32 master
__global__ __launch_bounds__(256) void k_prop1(const float* __restrict__ gs,
        const unsigned short* __restrict__ gh, unsigned short* __restrict__ gout,
        const int* __restrict__ offs, const int* __restrict__ adj,
        const float* __restrict__ d2a, int N) {
    int t = threadIdx.x;
    int lane = t & 63;
    int g = lane >> 4;
    int q = lane & 15;
    int n = blockIdx.x * 4 + (t >> 6);
    if (n >= N) return;
    int beg = offs[n], end = offs[n + 1];
    float ax = 0.f, ay = 0.f, az = 0.f, aw = 0.f;
    int e = beg + g;
    for (; e + 12 < end; e += 16) {
        int s0 = adj[e], s1 = adj[e + 4], s2 = adj[e + 8], s3 = adj[e + 12];
        float4 f0 = bf4tof(*(const ushort4*)(gh + (size_t)s0 * 64 + 4 * q));
        float4 f1 = bf4tof(*(const ushort4*)(gh + (size_t)s1 * 64 + 4 * q));
        float4 f2 = bf4tof(*(const ushort4*)(gh + (size_t)s2 * 64 + 4 * q));
        float4 f3 = bf4tof(*(const ushort4*)(gh + (size_t)s3 * 64 + 4 * q));
        ax += (f0.x + f1.x) + (f2.x + f3.x);
        ay += (f0.y + f1.y) + (f2.y + f3.y);
        az += (f0.z + f1.z) + (f2.z + f3.z);
        aw += (f0.w + f1.w) + (f2.w + f3.w);
    }
    for (; e < end; e += 4) {
        int s = adj[e];
        float4 f = bf4tof(*(const ushort4*)(gh + (size_t)s * 64 + 4 * q));
        ax += f.x; ay += f.y; az += f.z; aw += f.w;
    }
    ax += __shfl_xor(ax, 16); ay += __shfl_xor(ay, 16);
    az += __shfl_xor(az, 16); aw += __shfl_xor(aw, 16);
    ax += __shfl_xor(ax, 32); ay += __shfl_xor(ay, 32);
    az += __shfl_xor(az, 32); aw += __shfl_xor(aw, 32);
    if (g == 0) {
        float d2n = d2a[n];
        float4 self = ((const float4*)gs)[(size_t)n * 16 + q];
        ushort4 r;
        r.x = bf16rn(fmaf(-d2n, ax, self.x));
        r.y = bf16rn(fmaf(-d2n, ay, self.y));
        r.z = bf16rn(fmaf(-d2n, az, self.z));
        r.w = bf16rn(fmaf(-d2n, aw, self.w));
        *(ushort4*)(gout + (size_t)n * 64 + 4 * q) = r;
    }
}

// ---- prop2: gs2(fp32) = gs1h - d2[n] * sum_src gs1h[src] ----
__global__ __launch_bounds__(256) void k_prop2(const unsigned short* __restrict__ gh,
        float* __restrict__ gsn, const int* __restrict__ offs,
        const int* __restrict__ adj, const float* __restrict__ d2a, int N) {
    int t = threadIdx.x;
    int lane = t & 63;
    int g = lane >> 4;
    int q = lane & 15;
    int n = blockIdx.x * 4 + (t >> 6);
    if (n >= N) return;
    int beg = offs[n], end = offs[n + 1];
    float ax = 0.f, ay = 0.f, az = 0.f, aw = 0.f;
    int e = beg + g;
    for (; e + 12 < end; e += 16) {
        int s0 = adj[e], s1 = adj[e + 4], s2 = adj[e + 8], s3 = adj[e + 12];
        float4 f0 = bf4tof(*(const ushort4*)(gh + (size_t)s0 * 64 + 4 * q));
        float4 f1 = bf4tof(*(const ushort4*)(gh + (size_t)s1 * 64 + 4 * q));
        float4 f2 = bf4tof(*(const ushort4*)(gh + (size_t)s2 * 64 + 4 * q));
        float4 f3 = bf4tof(*(const ushort4*)(gh + (size_t)s3 * 64 + 4 * q));
        ax += (f0.x + f1.x) + (f2.x + f3.x);
        ay += (f0.y + f1.y) + (f2.y + f3.y);
        az += (f0.z + f1.z) + (f2.z + f3.z);
        aw += (f0.w + f1.w) + (f2.w + f3.w);
    }
    for (; e < end; e += 4) {
        int s = adj[e];
        float4 f = bf4tof(*(const ushort4*)(gh + (size_t)s * 64 + 4 * q));
        ax += f.x; ay += f.y; az += f.z; aw += f.w;
    }
    ax += __shfl_xor(ax, 16); ay += __shfl_xor(ay, 16);
    az += __shfl_xor(az, 16); aw += __shfl_xor(aw, 16);
    ax += __shfl_xor(ax, 32); ay += __shfl_xor(ay, 32);
    az += __shfl_xor(az, 32); aw += __shfl_xor(aw, 32);
    if (g == 0) {
        float d2n = d2a[n];
        float4 self = bf4tof(*(const ushort4*)(gh + (size_t)n * 64 + 4 * q));
        float4 r;
        r.x = fmaf(-d2n, ax, self.x);
        r.y = fmaf(-d2n, ay, self.y);
        r.z = fmaf(-d2n, az, self.z);
        r.w = fmaf(-d2n, aw, self.w);
        ((float4*)gsn)[(size_t)n * 16 + q] = r;
    }
}

// ---- final fused head: gs0 fp32, gs1 bf16, gs2 fp32 ----
__global__ __launch_bounds__(256) void k_final(const float* __restrict__ gs0,
        const unsigned short* __restrict__ gs1h, const float* __restrict__ gs2,
        const float* __restrict__ Wm1, const float* __restrict__ bm1,
        const float* __restrict__ Wm2, const float* __restrict__ bm2,
        const float* __restrict__ rda, float* __restrict__ out, int N) {
    __shared__ float Al[64 * KP];
    __shared__ float Bl[64 * 64];
    int t = threadIdx.x;
    int tx = t & 15, ty = t >> 4;
    int nb = blockIdx.x * 64;
    float acc[4][4] = {{0}};
    for (int p = 0; p < 3; ++p) {
        #pragma unroll
        for (int pp = 0; pp < 4; ++pp) {
            int nl = ty + 16 * pp;
            int nn = nb + nl; if (nn >= N) nn = N - 1;
            float4 v;
            if (p == 0)      v = ((const float4*)(gs0 + (size_t)nn * 64))[tx];
            else if (p == 1) v = bf4tof(*(const ushort4*)(gs1h + (size_t)nn * 64 + 4 * tx));
            else             v = ((const float4*)(gs2 + (size_t)nn * 64))[tx];
            *(float4*)&Al[nl * KP + 4 * tx] = v;
            int k = nl;
            float4 w0 = ((const float4*)(Wm1 + (size_t)k * 64))[tx];
            float4 w1 = ((const float4*)(Wm1 + (size_t)(64 + k) * 64))[tx];
            float4 w2 = ((const float4*)(Wm1 + (size_t)(128 + k) * 64))[tx];
            float4 mv;
            if (p == 0) {
                mv.x = 3.0f * w0.x; mv.y = 3.0f * w0.y;
                mv.z = 3.0f * w0.z; mv.w = 3.0f * w0.w;
            } else if (p == 1) {
                mv.x = fmaf(-3.0f, w0.x, 3.0f * w1.x);
                mv.y = fmaf(-3.0f, w0.y, 3.0f * w1.y);
                mv.z = fmaf(-3.0f, w0.z, 3.0f * w1.z);
                mv.w = fmaf(-3.0f, w0.w, 3.0f * w1.w);
            } else {
                mv.x = 0.75f * (w0.x + w2.x) - 1.5f * w1.x;
                mv.y = 0.75f * (w0.y + w2.y) - 1.5f * w1.y;
                mv.z = 0.75f * (w0.z + w2.z) - 1.5f * w1.z;
                mv.w = 0.75f * (w0.w + w2.w) - 1.5f * w1.w;
            }
            *(float4*)&Bl[k * 64 + 4 * tx] = mv;
        }
        __syncthreads();
        #pragma unroll 4
        for (int k = 0; k < 64; ++k) {
            float a0 = Al[(4 * ty + 0) * KP + k];
            float a1 = Al[(4 * ty + 1) * KP + k];
            float a2 = Al[(4 * ty + 2) * KP + k];
            float a3 = Al[(4 * ty + 3) * KP + k];
            float4 bv = *(const float4*)&Bl[k * 64 + 4 * tx];
            acc[0][0] = fmaf(a0, bv.x, acc[0][0]); acc[0][1] = fmaf(a0, bv.y, acc[0][1]);
            acc[0][2] = fmaf(a0, bv.z, acc[0][2]); acc[0][3] = fmaf(a0, bv.w, acc[0][3]);
            acc[1][0] = fmaf(a1, bv.x, acc[1][0]); acc[1][1] = fmaf(a1, bv.y, acc[1][1]);
            acc[1][2] = fmaf(a1, bv.z, acc[1][2]); acc[1][3] = fmaf(a1, bv.w, acc[1][3]);
            acc[2][0] = fmaf(a2, bv.x, acc[2][0]); acc[2][1] = fmaf(a2, bv.y, acc[2][1]);
            acc[2][2] = fmaf(a2, bv.z, acc[2][2]); acc[2][3] = fmaf(a2, bv.w, acc[2][3]);
            acc[3][0] = fmaf(a3, bv.x, acc[3][0]); acc[3][1] = fmaf(a3, bv.y, acc[3][1]);
            acc[3][2] = fmaf(a3, bv.z, acc[3][2]); acc[3][3] = fmaf(a3, bv.w, acc[3][3]);
        }
        __syncthreads();
    }
    float4 bmv = ((const float4*)bm1)[tx];
    float4 wa = ((const float4*)Wm2)[2 * tx];
    float4 wb = ((const float4*)Wm2)[2 * tx + 1];
    float bo0 = bm2[0], bo1 = bm2[1];
    #pragma unroll
    for (int i = 0; i < 4; ++i) {
        int n = nb + 4 * ty + i;
        float rdn = rda[(n < N) ? n : (N - 1)];
        float h0 = fmaxf(fmaf(rdn, acc[i][0], bmv.x), 0.f);
        float h1 = fmaxf(fmaf(rdn, acc[i][1], bmv.y), 0.f);
        float h2 = fmaxf(fmaf(rdn, acc[i][2], bmv.z), 0.f);
        float h3 = fmaxf(fmaf(rdn, acc[i][3], bmv.w), 0.f);
        float p0 = h0 * wa.x + h1 * wa.z + h2 * wb.x + h3 * wb.z;
        float p1 = h0 * wa.y + h1 * wa.w + h2 * wb.y + h3 * wb.w;
        #pragma unroll
        for (int m = 1; m < 16; m <<= 1) {
            p0 += __shfl_xor(p0, m);
            p1 += __shfl_xor(p1, m);
        }
        if (tx == 0 && n < N) {
            out[(size_t)n * 2 + 0] = p0 + bo0;
            out[(size_t)n * 2 + 1] = p1 + bo1;
        }
    }
}

extern "C" void kernel_launch(void* const* d_in, const int* in_sizes, int n_in,
                              void* d_out, int out_size, void* d_ws, size_t ws_size,
                              hipStream_t stream) {
    const float* x   = (const float*)d_in[0];
    const int*   ei  = (const int*)d_in[1];
    const float* W1  = (const float*)d_in[2];
    const float* b1  = (const float*)d_in[3];
    const float* W2  = (const float*)d_in[4];
    const float* b2  = (const float*)d_in[5];
    const float* Wm1 = (const float*)d_in[6];
    const float* bm1 = (const float*)d_in[7];
    const float* Wm2 = (const float*)d_in[8];
    const float* bm2 = (const float*)d_in[9];
    float* out = (float*)d_out;

    int* ws = (int*)d_ws;
    int*   cnt   = ws + OFF_CNT;
    int*   bbase = ws + OFF_BBASE;
    int*   offs  = ws + OFF_OFFS;
    float* d2a   = (float*)(ws + OFF_D2);
    float* rda   = (float*)(ws + OFF_RD);
    float* dinva = (float*)(ws + OFF_DINV);
    int*   adj   = ws + OFF_ADJ;
    unsigned short* gs0h = (unsigned short*)(ws + OFF_H0);
    unsigned short* gs1h = (unsigned short*)(ws + OFF_H1);
    int*   binned = ws + OFF_BUFA;            // dead after cfill; then gs2 fp32
    float* gs2   = (float*)(ws + OFF_BUFA);
    float* gs0   = (float*)(ws + OFF_BUFB);

    const int* srcp = ei;
    const int* dstp = ei + N_EDGES;

    hipMemsetAsync(cnt, 0, 256 * sizeof(int), stream);

    k_bin<<<(N_EDGES + 4095) / 4096, 256, 0, stream>>>(srcp, dstp, cnt, binned, N_EDGES);
    k_bscan<<<1, 256, 0, stream>>>(cnt, bbase, offs);
    k_cfill<<<NBKT, 256, 0, stream>>>(binned, cnt, bbase, offs, adj, d2a, rda, dinva);

    int nblk = (N_NODES + 63) / 64;
    k_gemm12<<<nblk, 256, 0, stream>>>(x, W1, b1, W2, b2, dinva, gs0, gs0h, N_NODES);

    k_prop1<<<(N_NODES + 3) / 4, 256, 0, stream>>>(gs0, gs0h, gs1h, offs, adj, d2a, N_NODES);
    k_prop2<<<(N_NODES + 3) / 4, 256, 0, stream>>>(gs1h, gs2, offs, adj, d2a, N_NODES);

    k_final<<<nblk, 256, 0, stream>>>(gs0, gs1h, gs2, Wm1, bm1, Wm2, bm2, rda, out, N_NODES);
}

// Round 7
// 316.204 us; speedup vs baseline: 1.2781x; 1.0193x over previous
//
#include <hip/hip_runtime.h>
#include <math.h>

#define N_NODES 100000
#define N_EDGES 1600000
#define IN_F 128
#define H_F 64
#define KP 68        // padded LDS leading dim for A tiles

#define NBKT 196     // ceil(100000/512) buckets of 512 nodes
#define BSEG 16384   // per-bucket segment capacity
#define BCAP 14336   // LDS staging capacity for adj per bucket (56KB)

// workspace layout in 4-byte words (~46 MB total)
#define NP        100096
#define OFF_CNT   0                           // int[256]
#define OFF_OFFS  256                         // int[N+1]
#define OFF_D2    (256 + NP + 64)             // float[NP]
#define OFF_RD    (OFF_D2 + NP)               // float[NP]
#define OFF_DINV  (OFF_RD + NP)               // float[NP]
#define OFF_ADJ   (OFF_DINV + NP)             // int[N_EDGES]
#define OFF_H0    (OFF_ADJ + N_EDGES)         // ushort[N*64] bf16 gs0
#define OFF_H1    (OFF_H0 + N_NODES*32)       // ushort[N*64] bf16 gs1; binned aliases H1+H2
#define OFF_H2    (OFF_H1 + N_NODES*32)       // ushort[N*64] bf16 gs2

__device__ __forceinline__ unsigned short bf16rn(float f) {
    unsigned u = __float_as_uint(f);
    u += 0x7FFFu + ((u >> 16) & 1u);
    return (unsigned short)(u >> 16);
}
__device__ __forceinline__ float4 bf4tof(ushort4 h) {
    float4 f;
    f.x = __uint_as_float((unsigned)h.x << 16);
    f.y = __uint_as_float((unsigned)h.y << 16);
    f.z = __uint_as_float((unsigned)h.z << 16);
    f.w = __uint_as_float((unsigned)h.w << 16);
    return f;
}
#define UNPK(u, lo, hi) { lo = __uint_as_float((u) << 16); hi = __uint_as_float((u) & 0xFFFF0000u); }

// ---- pass A: bin edges by dst>>9, packed (local<<17 | src) ----
__global__ __launch_bounds__(256) void k_bin(const int* __restrict__ src,
        const int* __restrict__ dst, int* __restrict__ cnt,
        int* __restrict__ binned, int E) {
    __shared__ int hist[NBKT];
    __shared__ int curb[NBKT];
    int t = threadIdx.x;
    for (int i = t; i < NBKT; i += 256) hist[i] = 0;
    __syncthreads();
    int base = blockIdx.x * 4096 + t;
    int d[16];
    #pragma unroll
    for (int i = 0; i < 16; ++i) {
        int e = base + i * 256;
        int dd = (e < E) ? dst[e] : -1;
        d[i] = dd;
        if (dd >= 0) atomicAdd(&hist[dd >> 9], 1);
    }
    __syncthreads();
    for (int i = t; i < NBKT; i += 256) {
        int h = hist[i];
        curb[i] = (h > 0) ? atomicAdd(&cnt[i], h) : 0;
    }
    __syncthreads();
    #pragma unroll
    for (int i = 0; i < 16; ++i) {
        int e = base + i * 256;
        if (e < E) {
            int s = src[e];
            int dd = d[i];
            int b = dd >> 9;
            int p = atomicAdd(&curb[b], 1);
            if (p < BSEG) binned[b * BSEG + p] = ((dd & 511) << 17) | s;
        }
    }
}

// ---- pass B: per-bucket CSR fill; each block scans the 196 counts itself ----
__global__ __launch_bounds__(256) void k_cfill(const int* __restrict__ binned,
        const int* __restrict__ cnt, int* __restrict__ offs, int* __restrict__ adj,
        float* __restrict__ d2a, float* __restrict__ rda, float* __restrict__ dinva) {
    __shared__ int csum[256];
    __shared__ int degl[512];
    __shared__ int offl[512];
    __shared__ int curl[512];
    __shared__ int wsum[4];
    __shared__ int adjl[BCAP];
    int b = blockIdx.x, t = threadIdx.x;
    // prefix over bucket counts (inclusive scan in csum)
    int cv = (t < NBKT) ? cnt[t] : 0;
    csum[t] = cv;
    __syncthreads();
    #pragma unroll
    for (int off = 1; off < 256; off <<= 1) {
        int u = (t >= off) ? csum[t - off] : 0;
        __syncthreads();
        csum[t] += u;
        __syncthreads();
    }
    int baseb = (b == 0) ? 0 : csum[b - 1];
    int cntb = csum[b] - baseb;
    if (b == 0 && t == 0) offs[N_NODES] = N_EDGES;
    int n0 = b << 9;
    const int* bp = binned + b * BSEG;
    degl[2 * t] = 0; degl[2 * t + 1] = 0;
    __syncthreads();
    for (int i = t; i < cntb; i += 256) {
        int w = bp[i];
        atomicAdd(&degl[w >> 17], 1);
    }
    __syncthreads();
    int d0 = degl[2 * t], d1 = degl[2 * t + 1];
    int tot = d0 + d1;
    int lane = t & 63, wid = t >> 6;
    int inc = tot;
    #pragma unroll
    for (int off = 1; off < 64; off <<= 1) {
        int v = __shfl_up(inc, off, 64);
        if (lane >= off) inc += v;
    }
    if (lane == 63) wsum[wid] = inc;
    __syncthreads();
    int wb = 0;
    for (int w = 0; w < wid; ++w) wb += wsum[w];
    int excl = wb + inc - tot;
    offl[2 * t] = excl;          curl[2 * t] = excl;
    offl[2 * t + 1] = excl + d0; curl[2 * t + 1] = excl + d0;
    __syncthreads();
    #pragma unroll
    for (int rep = 0; rep < 2; ++rep) {
        int i = t + rep * 256;
        int n = n0 + i;
        if (n < N_NODES) {
            offs[n] = baseb + offl[i];
            float df = (float)degl[i];
            if (df < 1.f) df = 1.f;
            float di = 1.0f / sqrtf(df);
            dinva[n] = di;
            d2a[n] = di * di;
            rda[n] = sqrtf(df);
        }
    }
    for (int i = t; i < cntb; i += 256) {
        int w = bp[i];
        int loc = w >> 17;
        int s = w & 0x1FFFF;
        int p = atomicAdd(&curl[loc], 1);
        if (p < BCAP) adjl[p] = s;
        else adj[baseb + p] = s;
    }
    __syncthreads();
    int lim = cntb < BCAP ? cntb : BCAP;
    for (int i = t; i < lim; i += 256) adj[baseb + i] = adjl[i];
}

// ======= fused MLP: gs0h = bf16(dinv .* relu(relu(x@W1+b1)@W2+b2)) ==========
__global__ __launch_bounds__(256) void k_gemm12(const float* __restrict__ x,
        const float* __restrict__ W1, const float* __restrict__ b1,
        const float* __restrict__ W2, const float* __restrict__ b2,
        const float* __restrict__ dinva, unsigned short* __restrict__ gsh, int N) {
    __shared__ float Al[64 * KP];
    __shared__ float Bl[64 * 64];
    __shared__ float Hl[64 * KP];
    int t = threadIdx.x;
    int tx = t & 15, ty = t >> 4;
    int nb = blockIdx.x * 64;
    float acc[4][4] = {{0}};
    for (int p = 0; p < 2; ++p) {
        #pragma unroll
        for (int pp = 0; pp < 4; ++pp) {
            int nl = ty + 16 * pp;
            int nn = nb + nl; if (nn >= N) nn = N - 1;
            float4 v = ((const float4*)(x + (size_t)nn * IN_F + p * 64))[tx];
            *(float4*)&Al[nl * KP + 4 * tx] = v;
        }
        #pragma unroll
        for (int pp = 0; pp < 4; ++pp) {
            int k = ty + 16 * pp;
            float4 v = ((const float4*)(W1 + (size_t)(p * 64 + k) * 64))[tx];
            *(float4*)&Bl[k * 64 + 4 * tx] = v;
        }
        __syncthreads();
        #pragma unroll 4
        for (int k = 0; k < 64; ++k) {
            float a0 = Al[(4 * ty + 0) * KP + k];
            float a1 = Al[(4 * ty + 1) * KP + k];
            float a2 = Al[(4 * ty + 2) * KP + k];
            float a3 = Al[(4 * ty + 3) * KP + k];
            float4 bv = *(const float4*)&Bl[k * 64 + 4 * tx];
            acc[0][0] = fmaf(a0, bv.x, acc[0][0]); acc[0][1] = fmaf(a0, bv.y, acc[0][1]);
            acc[0][2] = fmaf(a0, bv.z, acc[0][2]); acc[0][3] = fmaf(a0, bv.w, acc[0][3]);
            acc[1][0] = fmaf(a1, bv.x, acc[1][0]); acc[1][1] = fmaf(a1, bv.y, acc[1][1]);
            acc[1][2] = fmaf(a1, bv.z, acc[1][2]); acc[1][3] = fmaf(a1, bv.w, acc[1][3]);
            acc[2][0] = fmaf(a2, bv.x, acc[2][0]); acc[2][1] = fmaf(a2, bv.y, acc[2][1]);
            acc[2][2] = fmaf(a2, bv.z, acc[2][2]); acc[2][3] = fmaf(a2, bv.w, acc[2][3]);
            acc[3][0] = fmaf(a3, bv.x, acc[3][0]); acc[3][1] = fmaf(a3, bv.y, acc[3][1]);
            acc[3][2] = fmaf(a3, bv.z, acc[3][2]); acc[3][3] = fmaf(a3, bv.w, acc[3][3]);
        }
        __syncthreads();
    }
    {
        float4 bias = ((const float4*)b1)[tx];
        #pragma unroll
        for (int i = 0; i < 4; ++i) {
            float4 r;
            r.x = fmaxf(acc[i][0] + bias.x, 0.f);
            r.y = fmaxf(acc[i][1] + bias.y, 0.f);
            r.z = fmaxf(acc[i][2] + bias.z, 0.f);
            r.w = fmaxf(acc[i][3] + bias.w, 0.f);
            *(float4*)&Hl[(4 * ty + i) * KP + 4 * tx] = r;
            acc[i][0] = 0.f; acc[i][1] = 0.f; acc[i][2] = 0.f; acc[i][3] = 0.f;
        }
        #pragma unroll
        for (int pp = 0; pp < 4; ++pp) {
            int k = ty + 16 * pp;
            float4 v = ((const float4*)(W2 + (size_t)k * 64))[tx];
            *(float4*)&Bl[k * 64 + 4 * tx] = v;
        }
    }
    __syncthreads();
    #pragma unroll 4
    for (int k = 0; k < 64; ++k) {
        float a0 = Hl[(4 * ty + 0) * KP + k];
        float a1 = Hl[(4 * ty + 1) * KP + k];
        float a2 = Hl[(4 * ty + 2) * KP + k];
        float a3 = Hl[(4 * ty + 3) * KP + k];
        float4 bv = *(const float4*)&Bl[k * 64 + 4 * tx];
        acc[0][0] = fmaf(a0, bv.x, acc[0][0]); acc[0][1] = fmaf(a0, bv.y, acc[0][1]);
        acc[0][2] = fmaf(a0, bv.z, acc[0][2]); acc[0][3] = fmaf(a0, bv.w, acc[0][3]);
        acc[1][0] = fmaf(a1, bv.x, acc[1][0]); acc[1][1] = fmaf(a1, bv.y, acc[1][1]);
        acc[1][2] = fmaf(a1, bv.z, acc[1][2]); acc[1][3] = fmaf(a1, bv.w, acc[1][3]);
        acc[2][0] = fmaf(a2, bv.x, acc[2][0]); acc[2][1] = fmaf(a2, bv.y, acc[2][1]);
        acc[2][2] = fmaf(a2, bv.z, acc[2][2]); acc[2][3] = fmaf(a2, bv.w, acc[2][3]);
        acc[3][0] = fmaf(a3, bv.x, acc[3][0]); acc[3][1] = fmaf(a3, bv.y, acc[3][1]);
        acc[3][2] = fmaf(a3, bv.z, acc[3][2]); acc[3][3] = fmaf(a3, bv.w, acc[3][3]);
    }
    float4 bias2 = ((const float4*)b2)[tx];
    #pragma unroll
    for (int i = 0; i < 4; ++i) {
        int n = nb + 4 * ty + i;
        if (n < N) {
            float di = dinva[n];
            ushort4 hh;
            hh.x = bf16rn(di * fmaxf(acc[i][0] + bias2.x, 0.f));
            hh.y = bf16rn(di * fmaxf(acc[i][1] + bias2.y, 0.f));
            hh.z = bf16rn(di * fmaxf(acc[i][2] + bias2.z, 0.f));
            hh.w = bf16rn(di * fmaxf(acc[i][3] + bias2.w, 0.f));
            *(ushort4*)(gsh + (size_t)n * 64 + 4 * tx) = hh;
        }
    }
}

// ---- propagation (bf16 -> bf16): gout = gin - d2[n]*sum_src gin[src] ----
// 8 lanes/edge, uint4 (16B) loads: one wave VMEM instruction covers 8 edges.
__global__ __launch_bounds__(256) void k_prop(const unsigned short* __restrict__ gh,
        unsigned short* __restrict__ gout, const int* __restrict__ offs,
        const int* __restrict__ adj, const float* __restrict__ d2a, int N) {
    int t = threadIdx.x;
    int lane = t & 63;
    int g = lane >> 3;
    int q = lane & 7;
    int n = blockIdx.x * 4 + (t >> 6);
    if (n >= N) return;
    int beg = offs[n], end = offs[n + 1];
    float a0 = 0.f, a1 = 0.f, a2 = 0.f, a3 = 0.f;
    float a4 = 0.f, a5 = 0.f, a6 = 0.f, a7 = 0.f;
    int e = beg + g;
    for (; e + 24 < end; e += 32) {
        int s0 = adj[e], s1 = adj[e + 8], s2 = adj[e + 16], s3 = adj[e + 24];
        uint4 v0 = *(const uint4*)(gh + (size_t)s0 * 64 + 8 * q);
        uint4 v1 = *(const uint4*)(gh + (size_t)s1 * 64 + 8 * q);
        uint4 v2 = *(const uint4*)(gh + (size_t)s2 * 64 + 8 * q);
        uint4 v3 = *(const uint4*)(gh + (size_t)s3 * 64 + 8 * q);
        float l, h;
        UNPK(v0.x, l, h); a0 += l; a1 += h;
        UNPK(v0.y, l, h); a2 += l; a3 += h;
        UNPK(v0.z, l, h); a4 += l; a5 += h;
        UNPK(v0.w, l, h); a6 += l; a7 += h;
        UNPK(v1.x, l, h); a0 += l; a1 += h;
        UNPK(v1.y, l, h); a2 += l; a3 += h;
        UNPK(v1.z, l, h); a4 += l; a5 += h;
        UNPK(v1.w, l, h); a6 += l; a7 += h;
        UNPK(v2.x, l, h); a0 += l; a1 += h;
        UNPK(v2.y, l, h); a2 += l; a3 += h;
        UNPK(v2.z, l, h); a4 += l; a5 += h;
        UNPK(v2.w, l, h); a6 += l; a7 += h;
        UNPK(v3.x, l, h); a0 += l; a1 += h;
        UNPK(v3.y, l, h); a2 += l; a3 += h;
        UNPK(v3.z, l, h); a4 += l; a5 += h;
        UNPK(v3.w, l, h); a6 += l; a7 += h;
    }
    for (; e < end; e += 8) {
        int s = adj[e];
        uint4 v = *(const uint4*)(gh + (size_t)s * 64 + 8 * q);
        float l, h;
        UNPK(v.x, l, h); a0 += l; a1 += h;
        UNPK(v.y, l, h); a2 += l; a3 += h;
        UNPK(v.z, l, h); a4 += l; a5 += h;
        UNPK(v.w, l, h); a6 += l; a7 += h;
    }
    #pragma unroll
    for (int m = 8; m < 64; m <<= 1) {
        a0 += __shfl_xor(a0, m); a1 += __shfl_xor(a1, m);
        a2 += __shfl_xor(a2, m); a3 += __shfl_xor(a3, m);
        a4 += __shfl_xor(a4, m); a5 += __shfl_xor(a5, m);
        a6 += __shfl_xor(a6, m); a7 += __shfl_xor(a7, m);
    }
    if (g == 0) {
        float d2n = d2a[n];
        uint4 sv = *(const uint4*)(gh + (size_t)n * 64 + 8 * q);
        float l, h;
        uint4 r;
        UNPK(sv.x, l, h);
        r.x = ((unsigned)bf16rn(fmaf(-d2n, a1, h)) << 16) | bf16rn(fmaf(-d2n, a0, l));
        UNPK(sv.y, l, h);
        r.y = ((unsigned)bf16rn(fmaf(-d2n, a3, h)) << 16) | bf16rn(fmaf(-d2n, a2, l));
        UNPK(sv.z, l, h);
        r.z = ((unsigned)bf16rn(fmaf(-d2n, a5, h)) << 16) | bf16rn(fmaf(-d2n, a4, l));
        UNPK(sv.w, l, h);
        r.w = ((unsigned)bf16rn(fmaf(-d2n, a7, h)) << 16) | bf16rn(fmaf(-d2n, a6, l));
        *(uint4*)(gout + (size_t)n * 64 + 8 * q) = r;
    }
}

// ---- final fused head: all three slices bf16 ----
__global__ __launch_bounds__(256) void k_final(const unsigned short* __restrict__ g0h,
        const unsigned short* __restrict__ g1h, const unsigned short* __restrict__ g2h,
        const float* __restrict__ Wm1, const float* __restrict__ bm1,
        const float* __restrict__ Wm2, const float* __restrict__ bm2,
        const float* __restrict__ rda, float* __restrict__ out, int N) {
    __shared__ float Al[64 * KP];
    __shared__ float Bl[64 * 64];
    int t = threadIdx.x;
    int tx = t & 15, ty = t >> 4;
    int nb = blockIdx.x * 64;
    const unsigned short* bufs[3] = {g0h, g1h, g2h};
    float acc[4][4] = {{0}};
    for (int p = 0; p < 3; ++p) {
        const unsigned short* gp = bufs[p];
        #pragma unroll
        for (int pp = 0; pp < 4; ++pp) {
            int nl = ty + 16 * pp;
            int nn = nb + nl; if (nn >= N) nn = N - 1;
            float4 v = bf4tof(*(const ushort4*)(gp + (size_t)nn * 64 + 4 * tx));
            *(float4*)&Al[nl * KP + 4 * tx] = v;
            int k = nl;
            float4 w0 = ((const float4*)(Wm1 + (size_t)k * 64))[tx];
            float4 w1 = ((const float4*)(Wm1 + (size_t)(64 + k) * 64))[tx];
            float4 w2 = ((const float4*)(Wm1 + (size_t)(128 + k) * 64))[tx];
            float4 mv;
            if (p == 0) {
                mv.x = 3.0f * w0.x; mv.y = 3.0f * w0.y;
                mv.z = 3.0f * w0.z; mv.w = 3.0f * w0.w;
            } else if (p == 1) {
                mv.x = fmaf(-3.0f, w0.x, 3.0f * w1.x);
                mv.y = fmaf(-3.0f, w0.y, 3.0f * w1.y);
                mv.z = fmaf(-3.0f, w0.z, 3.0f * w1.z);
                mv.w = fmaf(-3.0f, w0.w, 3.0f * w1.w);
            } else {
                mv.x = 0.75f * (w0.x + w2.x) - 1.5f * w1.x;
                mv.y = 0.75f * (w0.y + w2.y) - 1.5f * w1.y;
                mv.z = 0.75f * (w0.z + w2.z) - 1.5f * w1.z;
                mv.w = 0.75f * (w0.w + w2.w) - 1.5f * w1.w;
            }
            *(float4*)&Bl[k * 64 + 4 * tx] = mv;
        }
        __syncthreads();
        #pragma unroll 4
        for (int k = 0; k < 64; ++k) {
            float a0 = Al[(4 * ty + 0) * KP + k];
            float a1 = Al[(4 * ty + 1) * KP + k];
            float a2 = Al[(4 * ty + 2) * KP + k];
            float a3 = Al[(4 * ty + 3) * KP + k];
            float4 bv = *(const float4*)&Bl[k * 64 + 4 * tx];
            acc[0][0] = fmaf(a0, bv.x, acc[0][0]); acc[0][1] = fmaf(a0, bv.y, acc[0][1]);
            acc[0][2] = fmaf(a0, bv.z, acc[0][2]); acc[0][3] = fmaf(a0, bv.w, acc[0][3]);
            acc[1][0] = fmaf(a1, bv.x, acc[1][0]); acc[1][1] = fmaf(a1, bv.y, acc[1][1]);
            acc[1][2] = fmaf(a1, bv.z, acc[1][2]); acc[1][3] = fmaf(a1, bv.w, acc[1][3]);
            acc[2][0] = fmaf(a2, bv.x, acc[2][0]); acc[2][1] = fmaf(a2, bv.y, acc[2][1]);
            acc[2][2] = fmaf(a2, bv.z, acc[2][2]); acc[2][3] = fmaf(a2, bv.w, acc[2][3]);
            acc[3][0] = fmaf(a3, bv.x, acc[3][0]); acc[3][1] = fmaf(a3, bv.y, acc[3][1]);
            acc[3][2] = fmaf(a3, bv.z, acc[3][2]); acc[3][3] = fmaf(a3, bv.w, acc[3][3]);
        }
        __syncthreads();
    }
    float4 bmv = ((const float4*)bm1)[tx];
    float4 wa = ((const float4*)Wm2)[2 * tx];
    float4 wb = ((const float4*)Wm2)[2 * tx + 1];
    float bo0 = bm2[0], bo1 = bm2[1];
    #pragma unroll
    for (int i = 0; i < 4; ++i) {
        int n = nb + 4 * ty + i;
        float rdn = rda[(n < N) ? n : (N - 1)];
        float h0 = fmaxf(fmaf(rdn, acc[i][0], bmv.x), 0.f);
        float h1 = fmaxf(fmaf(rdn, acc[i][1], bmv.y), 0.f);
        float h2 = fmaxf(fmaf(rdn, acc[i][2], bmv.z), 0.f);
        float h3 = fmaxf(fmaf(rdn, acc[i][3], bmv.w), 0.f);
        float p0 = h0 * wa.x + h1 * wa.z + h2 * wb.x + h3 * wb.z;
        float p1 = h0 * wa.y + h1 * wa.w + h2 * wb.y + h3 * wb.w;
        #pragma unroll
        for (int m = 1; m < 16; m <<= 1) {
            p0 += __shfl_xor(p0, m);
            p1 += __shfl_xor(p1, m);
        }
        if (tx == 0 && n < N) {
            out[(size_t)n * 2 + 0] = p0 + bo0;
            out[(size_t)n * 2 + 1] = p1 + bo1;
        }
    }
}

extern "C" void kernel_launch(void* const* d_in, const int* in_sizes, int n_in,
                              void* d_out, int out_size, void* d_ws, size_t ws_size,
                              hipStream_t stream) {
    const float* x   = (const float*)d_in[0];
    const int*   ei  = (const int*)d_in[1];
    const float* W1  = (const float*)d_in[2];
    const float* b1  = (const float*)d_in[3];
    const float* W2  = (const float*)d_in[4];
    const float* b2  = (const float*)d_in[5];
    const float* Wm1 = (const float*)d_in[6];
    const float* bm1 = (const float*)d_in[7];
    const float* Wm2 = (const float*)d_in[8];
    const float* bm2 = (const float*)d_in[9];
    float* out = (float*)d_out;

    int* ws = (int*)d_ws;
    int*   cnt   = ws + OFF_CNT;
    int*   offs  = ws + OFF_OFFS;
    float* d2a   = (float*)(ws + OFF_D2);
    float* rda   = (float*)(ws + OFF_RD);
    float* dinva = (float*)(ws + OFF_DINV);
    int*   adj   = ws + OFF_ADJ;
    unsigned short* gs0h = (unsigned short*)(ws + OFF_H0);
    unsigned short* gs1h = (unsigned short*)(ws + OFF_H1);
    unsigned short* gs2h = (unsigned short*)(ws + OFF_H2);
    int*   binned = ws + OFF_H1;   // aliases H1(+H2); dead before prop1 writes gs1h

    const int* srcp = ei;
    const int* dstp = ei + N_EDGES;

    hipMemsetAsync(cnt, 0, 256 * sizeof(int), stream);

    k_bin<<<(N_EDGES + 4095) / 4096, 256, 0, stream>>>(srcp, dstp, cnt, binned, N_EDGES);
    k_cfill<<<NBKT, 256, 0, stream>>>(binned, cnt, offs, adj, d2a, rda, dinva);

    int nblk = (N_NODES + 63) / 64;
    k_gemm12<<<nblk, 256, 0, stream>>>(x, W1, b1, W2, b2, dinva, gs0h, N_NODES);

    k_prop<<<(N_NODES + 3) / 4, 256, 0, stream>>>(gs0h, gs1h, offs, adj, d2a, N_NODES);
    k_prop<<<(N_NODES + 3) / 4, 256, 0, stream>>>(gs1h, gs2h, offs, adj, d2a, N_NODES);

    k_final<<<nblk, 256, 0, stream>>>(gs0h, gs1h, gs2h, Wm1, bm1, Wm2, bm2, rda, out, N_NODES);
}

// Round 8
// 285.437 us; speedup vs baseline: 1.4159x; 1.1078x over previous
//
#include <hip/hip_runtime.h>
#include <math.h>

#define N_NODES 100000
#define N_EDGES 1600000
#define IN_F 128
#define H_F 64
#define KP 68        // padded LDS leading dim for A tiles

#define NBKT 196     // ceil(100000/512) buckets of 512 nodes
#define BSEG 16384   // per-bucket segment capacity
#define BCAP 14336   // LDS staging capacity for adj per bucket (56KB)

// workspace layout in 4-byte words (~46 MB total)
#define NP        100096
#define OFF_CNT   0                           // int[256]
#define OFF_MPK   256                         // ushort[12288] packed bf16 Mcat (6144 words)
#define OFF_OFFS  (256 + 6144)                // int[N+1]
#define OFF_D2    (OFF_OFFS + NP + 64)        // float[NP]
#define OFF_RD    (OFF_D2 + NP)               // float[NP]
#define OFF_DINV  (OFF_RD + NP)               // float[NP]
#define OFF_ADJ   (OFF_DINV + NP)             // int[N_EDGES]
#define OFF_H0    (OFF_ADJ + N_EDGES)         // ushort[N*64] bf16 gs0
#define OFF_H1    (OFF_H0 + N_NODES*32)       // ushort[N*64] bf16 gs1; binned aliases H1+H2
#define OFF_H2    (OFF_H1 + N_NODES*32)       // ushort[N*64] bf16 gs2

typedef __attribute__((ext_vector_type(8))) short bf16x8;
typedef __attribute__((ext_vector_type(4))) float f32x4;

__device__ __forceinline__ unsigned short bf16rn(float f) {
    unsigned u = __float_as_uint(f);
    u += 0x7FFFu + ((u >> 16) & 1u);
    return (unsigned short)(u >> 16);
}
__device__ __forceinline__ float4 bf4tof(ushort4 h) {
    float4 f;
    f.x = __uint_as_float((unsigned)h.x << 16);
    f.y = __uint_as_float((unsigned)h.y << 16);
    f.z = __uint_as_float((unsigned)h.z << 16);
    f.w = __uint_as_float((unsigned)h.w << 16);
    return f;
}
#define UNPK(u, lo, hi) { lo = __uint_as_float((u) << 16); hi = __uint_as_float((u) & 0xFFFF0000u); }

// ---- pass A: bin edges by dst>>9, packed (local<<17 | src) ----
__global__ __launch_bounds__(256) void k_bin(const int* __restrict__ src,
        const int* __restrict__ dst, int* __restrict__ cnt,
        int* __restrict__ binned, int E) {
    __shared__ int hist[NBKT];
    __shared__ int curb[NBKT];
    int t = threadIdx.x;
    for (int i = t; i < NBKT; i += 256) hist[i] = 0;
    __syncthreads();
    int base = blockIdx.x * 4096 + t;
    int d[16];
    #pragma unroll
    for (int i = 0; i < 16; ++i) {
        int e = base + i * 256;
        int dd = (e < E) ? dst[e] : -1;
        d[i] = dd;
        if (dd >= 0) atomicAdd(&hist[dd >> 9], 1);
    }
    __syncthreads();
    for (int i = t; i < NBKT; i += 256) {
        int h = hist[i];
        curb[i] = (h > 0) ? atomicAdd(&cnt[i], h) : 0;
    }
    __syncthreads();
    #pragma unroll
    for (int i = 0; i < 16; ++i) {
        int e = base + i * 256;
        if (e < E) {
            int s = src[e];
            int dd = d[i];
            int b = dd >> 9;
            int p = atomicAdd(&curb[b], 1);
            if (p < BSEG) binned[b * BSEG + p] = ((dd & 511) << 17) | s;
        }
    }
}

// ---- pass B: per-bucket CSR fill; each block scans the 196 counts itself ----
__global__ __launch_bounds__(256) void k_cfill(const int* __restrict__ binned,
        const int* __restrict__ cnt, int* __restrict__ offs, int* __restrict__ adj,
        float* __restrict__ d2a, float* __restrict__ rda, float* __restrict__ dinva) {
    __shared__ int csum[256];
    __shared__ int degl[512];
    __shared__ int offl[512];
    __shared__ int curl[512];
    __shared__ int wsum[4];
    __shared__ int adjl[BCAP];
    int b = blockIdx.x, t = threadIdx.x;
    int cv = (t < NBKT) ? cnt[t] : 0;
    csum[t] = cv;
    __syncthreads();
    #pragma unroll
    for (int off = 1; off < 256; off <<= 1) {
        int u = (t >= off) ? csum[t - off] : 0;
        __syncthreads();
        csum[t] += u;
        __syncthreads();
    }
    int baseb = (b == 0) ? 0 : csum[b - 1];
    int cntb = csum[b] - baseb;
    if (b == 0 && t == 0) offs[N_NODES] = N_EDGES;
    int n0 = b << 9;
    const int* bp = binned + b * BSEG;
    degl[2 * t] = 0; degl[2 * t + 1] = 0;
    __syncthreads();
    for (int i = t; i < cntb; i += 256) {
        int w = bp[i];
        atomicAdd(&degl[w >> 17], 1);
    }
    __syncthreads();
    int d0 = degl[2 * t], d1 = degl[2 * t + 1];
    int tot = d0 + d1;
    int lane = t & 63, wid = t >> 6;
    int inc = tot;
    #pragma unroll
    for (int off = 1; off < 64; off <<= 1) {
        int v = __shfl_up(inc, off, 64);
        if (lane >= off) inc += v;
    }
    if (lane == 63) wsum[wid] = inc;
    __syncthreads();
    int wb = 0;
    for (int w = 0; w < wid; ++w) wb += wsum[w];
    int excl = wb + inc - tot;
    offl[2 * t] = excl;          curl[2 * t] = excl;
    offl[2 * t + 1] = excl + d0; curl[2 * t + 1] = excl + d0;
    __syncthreads();
    #pragma unroll
    for (int rep = 0; rep < 2; ++rep) {
        int i = t + rep * 256;
        int n = n0 + i;
        if (n < N_NODES) {
            offs[n] = baseb + offl[i];
            float df = (float)degl[i];
            if (df < 1.f) df = 1.f;
            float di = 1.0f / sqrtf(df);
            dinva[n] = di;
            d2a[n] = di * di;
            rda[n] = sqrtf(df);
        }
    }
    for (int i = t; i < cntb; i += 256) {
        int w = bp[i];
        int loc = w >> 17;
        int s = w & 0x1FFFF;
        int p = atomicAdd(&curl[loc], 1);
        if (p < BCAP) adjl[p] = s;
        else adj[baseb + p] = s;
    }
    __syncthreads();
    int lim = cntb < BCAP ? cntb : BCAP;
    for (int i = t; i < lim; i += 256) adj[baseb + i] = adjl[i];
}

// ---- Mcat packed bf16 in MFMA-B-fragment order ----
// element (s,qd,n,j) = M[k = s*32+qd*8+j][n], idx = ((s*4+qd)*64+n)*8+j
__global__ __launch_bounds__(256) void k_mcat(const float* __restrict__ Wm1,
                                              unsigned short* __restrict__ mpk) {
    int idx = blockIdx.x * 256 + threadIdx.x;
    if (idx >= 12288) return;
    int j = idx & 7;
    int n = (idx >> 3) & 63;
    int qd = (idx >> 9) & 3;
    int s = idx >> 11;
    int k = s * 32 + qd * 8 + j;     // 0..191
    int p = k >> 6;                  // gs slice
    int kk = k & 63;
    float w0 = Wm1[kk * 64 + n];
    float w1 = Wm1[(64 + kk) * 64 + n];
    float w2 = Wm1[(128 + kk) * 64 + n];
    float v;
    if (p == 0)      v = 3.0f * w0;
    else if (p == 1) v = 3.0f * (w1 - w0);
    else             v = 0.75f * (w0 + w2) - 1.5f * w1;
    mpk[idx] = bf16rn(v);
}

// ======= fused MLP: gs0h = bf16(dinv .* relu(relu(x@W1+b1)@W2+b2)) ==========
__global__ __launch_bounds__(256) void k_gemm12(const float* __restrict__ x,
        const float* __restrict__ W1, const float* __restrict__ b1,
        const float* __restrict__ W2, const float* __restrict__ b2,
        const float* __restrict__ dinva, unsigned short* __restrict__ gsh, int N) {
    __shared__ float Al[64 * KP];
    __shared__ float Bl[64 * 64];
    __shared__ float Hl[64 * KP];
    int t = threadIdx.x;
    int tx = t & 15, ty = t >> 4;
    int nb = blockIdx.x * 64;
    float acc[4][4] = {{0}};
    for (int p = 0; p < 2; ++p) {
        #pragma unroll
        for (int pp = 0; pp < 4; ++pp) {
            int nl = ty + 16 * pp;
            int nn = nb + nl; if (nn >= N) nn = N - 1;
            float4 v = ((const float4*)(x + (size_t)nn * IN_F + p * 64))[tx];
            *(float4*)&Al[nl * KP + 4 * tx] = v;
        }
        #pragma unroll
        for (int pp = 0; pp < 4; ++pp) {
            int k = ty + 16 * pp;
            float4 v = ((const float4*)(W1 + (size_t)(p * 64 + k) * 64))[tx];
            *(float4*)&Bl[k * 64 + 4 * tx] = v;
        }
        __syncthreads();
        #pragma unroll 4
        for (int k = 0; k < 64; ++k) {
            float a0 = Al[(4 * ty + 0) * KP + k];
            float a1 = Al[(4 * ty + 1) * KP + k];
            float a2 = Al[(4 * ty + 2) * KP + k];
            float a3 = Al[(4 * ty + 3) * KP + k];
            float4 bv = *(const float4*)&Bl[k * 64 + 4 * tx];
            acc[0][0] = fmaf(a0, bv.x, acc[0][0]); acc[0][1] = fmaf(a0, bv.y, acc[0][1]);
            acc[0][2] = fmaf(a0, bv.z, acc[0][2]); acc[0][3] = fmaf(a0, bv.w, acc[0][3]);
            acc[1][0] = fmaf(a1, bv.x, acc[1][0]); acc[1][1] = fmaf(a1, bv.y, acc[1][1]);
            acc[1][2] = fmaf(a1, bv.z, acc[1][2]); acc[1][3] = fmaf(a1, bv.w, acc[1][3]);
            acc[2][0] = fmaf(a2, bv.x, acc[2][0]); acc[2][1] = fmaf(a2, bv.y, acc[2][1]);
            acc[2][2] = fmaf(a2, bv.z, acc[2][2]); acc[2][3] = fmaf(a2, bv.w, acc[2][3]);
            acc[3][0] = fmaf(a3, bv.x, acc[3][0]); acc[3][1] = fmaf(a3, bv.y, acc[3][1]);
            acc[3][2] = fmaf(a3, bv.z, acc[3][2]); acc[3][3] = fmaf(a3, bv.w, acc[3][3]);
        }
        __syncthreads();
    }
    {
        float4 bias = ((const float4*)b1)[tx];
        #pragma unroll
        for (int i = 0; i < 4; ++i) {
            float4 r;
            r.x = fmaxf(acc[i][0] + bias.x, 0.f);
            r.y = fmaxf(acc[i][1] + bias.y, 0.f);
            r.z = fmaxf(acc[i][2] + bias.z, 0.f);
            r.w = fmaxf(acc[i][3] + bias.w, 0.f);
            *(float4*)&Hl[(4 * ty + i) * KP + 4 * tx] = r;
            acc[i][0] = 0.f; acc[i][1] = 0.f; acc[i][2] = 0.f; acc[i][3] = 0.f;
        }
        #pragma unroll
        for (int pp = 0; pp < 4; ++pp) {
            int k = ty + 16 * pp;
            float4 v = ((const float4*)(W2 + (size_t)k * 64))[tx];
            *(float4*)&Bl[k * 64 + 4 * tx] = v;
        }
    }
    __syncthreads();
    #pragma unroll 4
    for (int k = 0; k < 64; ++k) {
        float a0 = Hl[(4 * ty + 0) * KP + k];
        float a1 = Hl[(4 * ty + 1) * KP + k];
        float a2 = Hl[(4 * ty + 2) * KP + k];
        float a3 = Hl[(4 * ty + 3) * KP + k];
        float4 bv = *(const float4*)&Bl[k * 64 + 4 * tx];
        acc[0][0] = fmaf(a0, bv.x, acc[0][0]); acc[0][1] = fmaf(a0, bv.y, acc[0][1]);
        acc[0][2] = fmaf(a0, bv.z, acc[0][2]); acc[0][3] = fmaf(a0, bv.w, acc[0][3]);
        acc[1][0] = fmaf(a1, bv.x, acc[1][0]); acc[1][1] = fmaf(a1, bv.y, acc[1][1]);
        acc[1][2] = fmaf(a1, bv.z, acc[1][2]); acc[1][3] = fmaf(a1, bv.w, acc[1][3]);
        acc[2][0] = fmaf(a2, bv.x, acc[2][0]); acc[2][1] = fmaf(a2, bv.y, acc[2][1]);
        acc[2][2] = fmaf(a2, bv.z, acc[2][2]); acc[2][3] = fmaf(a2, bv.w, acc[2][3]);
        acc[3][0] = fmaf(a3, bv.x, acc[3][0]); acc[3][1] = fmaf(a3, bv.y, acc[3][1]);
        acc[3][2] = fmaf(a3, bv.z, acc[3][2]); acc[3][3] = fmaf(a3, bv.w, acc[3][3]);
    }
    float4 bias2 = ((const float4*)b2)[tx];
    #pragma unroll
    for (int i = 0; i < 4; ++i) {
        int n = nb + 4 * ty + i;
        if (n < N) {
            float di = dinva[n];
            ushort4 hh;
            hh.x = bf16rn(di * fmaxf(acc[i][0] + bias2.x, 0.f));
            hh.y = bf16rn(di * fmaxf(acc[i][1] + bias2.y, 0.f));
            hh.z = bf16rn(di * fmaxf(acc[i][2] + bias2.z, 0.f));
            hh.w = bf16rn(di * fmaxf(acc[i][3] + bias2.w, 0.f));
            *(ushort4*)(gsh + (size_t)n * 64 + 4 * tx) = hh;
        }
    }
}

// ---- propagation (bf16 -> bf16): gout = gin - d2[n]*sum_src gin[src] ----
__global__ __launch_bounds__(256) void k_prop(const unsigned short* __restrict__ gh,
        unsigned short* __restrict__ gout, const int* __restrict__ offs,
        const int* __restrict__ adj, const float* __restrict__ d2a, int N) {
    int t = threadIdx.x;
    int lane = t & 63;
    int g = lane >> 3;
    int q = lane & 7;
    int n = blockIdx.x * 4 + (t >> 6);
    if (n >= N) return;
    int beg = offs[n], end = offs[n + 1];
    float a0 = 0.f, a1 = 0.f, a2 = 0.f, a3 = 0.f;
    float a4 = 0.f, a5 = 0.f, a6 = 0.f, a7 = 0.f;
    int e = beg + g;
    for (; e + 24 < end; e += 32) {
        int s0 = adj[e], s1 = adj[e + 8], s2 = adj[e + 16], s3 = adj[e + 24];
        uint4 v0 = *(const uint4*)(gh + (size_t)s0 * 64 + 8 * q);
        uint4 v1 = *(const uint4*)(gh + (size_t)s1 * 64 + 8 * q);
        uint4 v2 = *(const uint4*)(gh + (size_t)s2 * 64 + 8 * q);
        uint4 v3 = *(const uint4*)(gh + (size_t)s3 * 64 + 8 * q);
        float l, h;
        UNPK(v0.x, l, h); a0 += l; a1 += h;
        UNPK(v0.y, l, h); a2 += l; a3 += h;
        UNPK(v0.z, l, h); a4 += l; a5 += h;
        UNPK(v0.w, l, h); a6 += l; a7 += h;
        UNPK(v1.x, l, h); a0 += l; a1 += h;
        UNPK(v1.y, l, h); a2 += l; a3 += h;
        UNPK(v1.z, l, h); a4 += l; a5 += h;
        UNPK(v1.w, l, h); a6 += l; a7 += h;
        UNPK(v2.x, l, h); a0 += l; a1 += h;
        UNPK(v2.y, l, h); a2 += l; a3 += h;
        UNPK(v2.z, l, h); a4 += l; a5 += h;
        UNPK(v2.w, l, h); a6 += l; a7 += h;
        UNPK(v3.x, l, h); a0 += l; a1 += h;
        UNPK(v3.y, l, h); a2 += l; a3 += h;
        UNPK(v3.z, l, h); a4 += l; a5 += h;
        UNPK(v3.w, l, h); a6 += l; a7 += h;
    }
    for (; e < end; e += 8) {
        int s = adj[e];
        uint4 v = *(const uint4*)(gh + (size_t)s * 64 + 8 * q);
        float l, h;
        UNPK(v.x, l, h); a0 += l; a1 += h;
        UNPK(v.y, l, h); a2 += l; a3 += h;
        UNPK(v.z, l, h); a4 += l; a5 += h;
        UNPK(v.w, l, h); a6 += l; a7 += h;
    }
    #pragma unroll
    for (int m = 8; m < 64; m <<= 1) {
        a0 += __shfl_xor(a0, m); a1 += __shfl_xor(a1, m);
        a2 += __shfl_xor(a2, m); a3 += __shfl_xor(a3, m);
        a4 += __shfl_xor(a4, m); a5 += __shfl_xor(a5, m);
        a6 += __shfl_xor(a6, m); a7 += __shfl_xor(a7, m);
    }
    if (g == 0) {
        float d2n = d2a[n];
        uint4 sv = *(const uint4*)(gh + (size_t)n * 64 + 8 * q);
        float l, h;
        uint4 r;
        UNPK(sv.x, l, h);
        r.x = ((unsigned)bf16rn(fmaf(-d2n, a1, h)) << 16) | bf16rn(fmaf(-d2n, a0, l));
        UNPK(sv.y, l, h);
        r.y = ((unsigned)bf16rn(fmaf(-d2n, a3, h)) << 16) | bf16rn(fmaf(-d2n, a2, l));
        UNPK(sv.z, l, h);
        r.z = ((unsigned)bf16rn(fmaf(-d2n, a5, h)) << 16) | bf16rn(fmaf(-d2n, a4, l));
        UNPK(sv.w, l, h);
        r.w = ((unsigned)bf16rn(fmaf(-d2n, a7, h)) << 16) | bf16rn(fmaf(-d2n, a6, l));
        *(uint4*)(gout + (size_t)n * 64 + 8 * q) = r;
    }
}

// ---- MFMA head: wave = 16 nodes x 64 outs, K=192 over 3 bf16 slices ----
// A[m=lane&15][k=quad*8+j] direct 16B global loads; B pre-packed by k_mcat.
// C layout: col=lane&15 (out), row=quad*4+reg (node) [m89].
__global__ __launch_bounds__(256) void k_final(const unsigned short* __restrict__ g0h,
        const unsigned short* __restrict__ g1h, const unsigned short* __restrict__ g2h,
        const unsigned short* __restrict__ mpk, const float* __restrict__ bm1,
        const float* __restrict__ Wm2, const float* __restrict__ bm2,
        const float* __restrict__ rda, float* __restrict__ out, int N) {
    int t = threadIdx.x;
    int w = t >> 6, lane = t & 63;
    int c = lane & 15, qd = lane >> 4;
    int nbase = blockIdx.x * 64 + w * 16;
    if (nbase >= N) return;               // wave-uniform
    int node = nbase + c;
    int nclamp = (node < N) ? node : N - 1;
    const unsigned short* bufs[3] = {g0h, g1h, g2h};
    f32x4 acc0 = {0.f, 0.f, 0.f, 0.f};
    f32x4 acc1 = {0.f, 0.f, 0.f, 0.f};
    f32x4 acc2 = {0.f, 0.f, 0.f, 0.f};
    f32x4 acc3 = {0.f, 0.f, 0.f, 0.f};
    #pragma unroll
    for (int s = 0; s < 6; ++s) {
        const unsigned short* gp = bufs[s >> 1];
        int k0 = (s & 1) * 32;
        bf16x8 a = *(const bf16x8*)(gp + (size_t)nclamp * 64 + k0 + qd * 8);
        const unsigned short* mb = mpk + (size_t)((s * 4 + qd) * 64) * 8;
        bf16x8 b0 = *(const bf16x8*)(mb + (size_t)(c) * 8);
        bf16x8 b1 = *(const bf16x8*)(mb + (size_t)(16 + c) * 8);
        bf16x8 b2 = *(const bf16x8*)(mb + (size_t)(32 + c) * 8);
        bf16x8 b3 = *(const bf16x8*)(mb + (size_t)(48 + c) * 8);
        acc0 = __builtin_amdgcn_mfma_f32_16x16x32_bf16(a, b0, acc0, 0, 0, 0);
        acc1 = __builtin_amdgcn_mfma_f32_16x16x32_bf16(a, b1, acc1, 0, 0, 0);
        acc2 = __builtin_amdgcn_mfma_f32_16x16x32_bf16(a, b2, acc2, 0, 0, 0);
        acc3 = __builtin_amdgcn_mfma_f32_16x16x32_bf16(a, b3, acc3, 0, 0, 0);
    }
    // epilogue: h = relu(rd*acc + bm1); p = h @ Wm2; reduce over 16 cols
    float rdr[4];
    #pragma unroll
    for (int r = 0; r < 4; ++r) {
        int nd = nbase + qd * 4 + r;
        rdr[r] = rda[(nd < N) ? nd : N - 1];
    }
    float p0[4] = {0.f, 0.f, 0.f, 0.f};
    float p1[4] = {0.f, 0.f, 0.f, 0.f};
    #pragma unroll
    for (int ot = 0; ot < 4; ++ot) {
        int col = ot * 16 + c;
        float bmc = bm1[col];
        float wc0 = Wm2[col * 2 + 0];
        float wc1 = Wm2[col * 2 + 1];
        f32x4 a = (ot == 0) ? acc0 : (ot == 1) ? acc1 : (ot == 2) ? acc2 : acc3;
        #pragma unroll
        for (int r = 0; r < 4; ++r) {
            float h = fmaxf(fmaf(rdr[r], a[r], bmc), 0.f);
            p0[r] = fmaf(h, wc0, p0[r]);
            p1[r] = fmaf(h, wc1, p1[r]);
        }
    }
    #pragma unroll
    for (int m = 1; m < 16; m <<= 1) {
        #pragma unroll
        for (int r = 0; r < 4; ++r) {
            p0[r] += __shfl_xor(p0[r], m);
            p1[r] += __shfl_xor(p1[r], m);
        }
    }
    if (c == 0) {
        float bo0 = bm2[0], bo1 = bm2[1];
        #pragma unroll
        for (int r = 0; r < 4; ++r) {
            int nd = nbase + qd * 4 + r;
            if (nd < N) {
                float2 o;
                o.x = p0[r] + bo0;
                o.y = p1[r] + bo1;
                *(float2*)(out + (size_t)nd * 2) = o;
            }
        }
    }
}

extern "C" void kernel_launch(void* const* d_in, const int* in_sizes, int n_in,
                              void* d_out, int out_size, void* d_ws, size_t ws_size,
                              hipStream_t stream) {
    const float* x   = (const float*)d_in[0];
    const int*   ei  = (const int*)d_in[1];
    const float* W1  = (const float*)d_in[2];
    const float* b1  = (const float*)d_in[3];
    const float* W2  = (const float*)d_in[4];
    const float* b2  = (const float*)d_in[5];
    const float* Wm1 = (const float*)d_in[6];
    const float* bm1 = (const float*)d_in[7];
    const float* Wm2 = (const float*)d_in[8];
    const float* bm2 = (const float*)d_in[9];
    float* out = (float*)d_out;

    int* ws = (int*)d_ws;
    int*   cnt   = ws + OFF_CNT;
    unsigned short* mpk = (unsigned short*)(ws + OFF_MPK);
    int*   offs  = ws + OFF_OFFS;
    float* d2a   = (float*)(ws + OFF_D2);
    float* rda   = (float*)(ws + OFF_RD);
    float* dinva = (float*)(ws + OFF_DINV);
    int*   adj   = ws + OFF_ADJ;
    unsigned short* gs0h = (unsigned short*)(ws + OFF_H0);
    unsigned short* gs1h = (unsigned short*)(ws + OFF_H1);
    unsigned short* gs2h = (unsigned short*)(ws + OFF_H2);
    int*   binned = ws + OFF_H1;   // aliases H1(+H2); dead before prop1 writes gs1h

    const int* srcp = ei;
    const int* dstp = ei + N_EDGES;

    hipMemsetAsync(cnt, 0, 256 * sizeof(int), stream);

    k_mcat<<<48, 256, 0, stream>>>(Wm1, mpk);
    k_bin<<<(N_EDGES + 4095) / 4096, 256, 0, stream>>>(srcp, dstp, cnt, binned, N_EDGES);
    k_cfill<<<NBKT, 256, 0, stream>>>(binned, cnt, offs, adj, d2a, rda, dinva);

    int nblk = (N_NODES + 63) / 64;
    k_gemm12<<<nblk, 256, 0, stream>>>(x, W1, b1, W2, b2, dinva, gs0h, N_NODES);

    k_prop<<<(N_NODES + 3) / 4, 256, 0, stream>>>(gs0h, gs1h, offs, adj, d2a, N_NODES);
    k_prop<<<(N_NODES + 3) / 4, 256, 0, stream>>>(gs1h, gs2h, offs, adj, d2a, N_NODES);

    k_final<<<nblk, 256, 0, stream>>>(gs0h, gs1h, gs2h, mpk, bm1, Wm2, bm2, rda, out, N_NODES);
}

// Round 9
// 270.136 us; speedup vs baseline: 1.4961x; 1.0566x over previous
//
#include <hip/hip_runtime.h>
#include <math.h>

#define N_NODES 100000
#define N_EDGES 1600000
#define IN_F 128
#define H_F 64

#define NBKT 196     // ceil(100000/512) buckets of 512 nodes
#define BSEG 16384   // per-bucket segment capacity
#define BCAP 14336   // LDS staging capacity for adj per bucket (56KB)

// workspace layout in 4-byte words (~46.5 MB total)
#define NP        100096
#define OFF_CNT   0                           // int[256]
#define OFF_MPK   256                         // ushort[12288] packed bf16 Mcat
#define OFF_W1H   6400                        // ushort[8192] W1 hi, B-frag order
#define OFF_W1L   10496                       // ushort[8192] W1 lo
#define OFF_W2H   14592                       // ushort[4096] W2 hi
#define OFF_W2L   16640                       // ushort[4096] W2 lo
#define OFF_OFFS  18688                       // int[N+1]
#define OFF_D2    (OFF_OFFS + NP + 64)        // float[NP]
#define OFF_RD    (OFF_D2 + NP)               // float[NP]
#define OFF_DINV  (OFF_RD + NP)               // float[NP]
#define OFF_ADJ   (OFF_DINV + NP)             // int[N_EDGES]
#define OFF_H0    (OFF_ADJ + N_EDGES)         // ushort[N*64] bf16 gs0
#define OFF_H1    (OFF_H0 + N_NODES*32)       // ushort[N*64] bf16 gs1; binned aliases H1+H2
#define OFF_H2    (OFF_H1 + N_NODES*32)       // ushort[N*64] bf16 gs2

typedef __attribute__((ext_vector_type(8))) short bf16x8;
typedef __attribute__((ext_vector_type(4))) float f32x4;

__device__ __forceinline__ unsigned short bf16rn(float f) {
    unsigned u = __float_as_uint(f);
    u += 0x7FFFu + ((u >> 16) & 1u);
    return (unsigned short)(u >> 16);
}
#define UNPK(u, lo, hi) { lo = __uint_as_float((u) << 16); hi = __uint_as_float((u) & 0xFFFF0000u); }

// ---- prep: pack Mcat (theta-combined Wm1) + split-bf16 W1/W2 B-fragments ----
// mpk: (s,qd,n,j) = M[k=s*32+qd*8+j][n], idx = ((s*4+qd)*64+n)*8+j
// w1:  lin = ((ks*4+qd)*4+ot)*128 + c*8 + j -> W1[ks*32+qd*8+j][ot*16+c]
// w2:  lin = ((ks*4+qd)*4+ot)*128 + c*8 + j -> W2[ks*32+qd*8+j][ot*16+c]
__global__ __launch_bounds__(256) void k_prep(const float* __restrict__ Wm1,
        const float* __restrict__ W1, const float* __restrict__ W2,
        unsigned short* __restrict__ mpk,
        unsigned short* __restrict__ w1h, unsigned short* __restrict__ w1l,
        unsigned short* __restrict__ w2h, unsigned short* __restrict__ w2l) {
    int idx = blockIdx.x * 256 + threadIdx.x;
    if (idx < 12288) {
        int j = idx & 7;
        int n = (idx >> 3) & 63;
        int qd = (idx >> 9) & 3;
        int s = idx >> 11;
        int k = s * 32 + qd * 8 + j;
        int p = k >> 6;
        int kk = k & 63;
        float w0 = Wm1[kk * 64 + n];
        float w1 = Wm1[(64 + kk) * 64 + n];
        float w2 = Wm1[(128 + kk) * 64 + n];
        float v;
        if (p == 0)      v = 3.0f * w0;
        else if (p == 1) v = 3.0f * (w1 - w0);
        else             v = 0.75f * (w0 + w2) - 1.5f * w1;
        mpk[idx] = bf16rn(v);
    } else if (idx < 12288 + 8192) {
        int lin = idx - 12288;
        int j = lin & 7, cc = (lin >> 3) & 15, ot = (lin >> 7) & 3;
        int qd = (lin >> 9) & 3, ks = lin >> 11;
        float v = W1[(ks * 32 + qd * 8 + j) * 64 + ot * 16 + cc];
        unsigned short h = bf16rn(v);
        w1h[lin] = h;
        w1l[lin] = bf16rn(v - __uint_as_float((unsigned)h << 16));
    } else if (idx < 24576) {
        int lin = idx - 20480;
        int j = lin & 7, cc = (lin >> 3) & 15, ot = (lin >> 7) & 3;
        int qd = (lin >> 9) & 3, ks = lin >> 11;
        float v = W2[(ks * 32 + qd * 8 + j) * 64 + ot * 16 + cc];
        unsigned short h = bf16rn(v);
        w2h[lin] = h;
        w2l[lin] = bf16rn(v - __uint_as_float((unsigned)h << 16));
    }
}

// ---- pass A: bin edges by dst>>9, per-wave histograms + sub-range reserve ----
__global__ __launch_bounds__(256) void k_bin(const int* __restrict__ src,
        const int* __restrict__ dst, int* __restrict__ cnt,
        int* __restrict__ binned, int E) {
    __shared__ int hist[4][208];
    __shared__ int cur4[4][208];
    int t = threadIdx.x;
    int w = t >> 6;
    for (int i = t; i < 4 * 208; i += 256) (&hist[0][0])[i] = 0;
    __syncthreads();
    int base = blockIdx.x * 4096 + t;
    int d[16];
    #pragma unroll
    for (int i = 0; i < 16; ++i) {
        int e = base + i * 256;
        int dd = (e < E) ? dst[e] : -1;
        d[i] = dd;
        if (dd >= 0) atomicAdd(&hist[w][dd >> 9], 1);
    }
    __syncthreads();
    if (t < NBKT) {
        int h0 = hist[0][t], h1 = hist[1][t], h2 = hist[2][t], h3 = hist[3][t];
        int tot = h0 + h1 + h2 + h3;
        int b0 = (tot > 0) ? atomicAdd(&cnt[t], tot) : 0;
        cur4[0][t] = b0;
        cur4[1][t] = b0 + h0;
        cur4[2][t] = b0 + h0 + h1;
        cur4[3][t] = b0 + h0 + h1 + h2;
    }
    __syncthreads();
    #pragma unroll
    for (int i = 0; i < 16; ++i) {
        int e = base + i * 256;
        if (e < E) {
            int s = src[e];
            int dd = d[i];
            int b = dd >> 9;
            int p = atomicAdd(&cur4[w][b], 1);
            if (p < BSEG) binned[b * BSEG + p] = ((dd & 511) << 17) | s;
        }
    }
}

// ---- pass B: per-bucket CSR fill; each block scans the 196 counts itself ----
__global__ __launch_bounds__(256) void k_cfill(const int* __restrict__ binned,
        const int* __restrict__ cnt, int* __restrict__ offs, int* __restrict__ adj,
        float* __restrict__ d2a, float* __restrict__ rda, float* __restrict__ dinva) {
    __shared__ int csum[256];
    __shared__ int degl[512];
    __shared__ int offl[512];
    __shared__ int curl[512];
    __shared__ int wsum[4];
    __shared__ int adjl[BCAP];
    int b = blockIdx.x, t = threadIdx.x;
    int cv = (t < NBKT) ? cnt[t] : 0;
    csum[t] = cv;
    __syncthreads();
    #pragma unroll
    for (int off = 1; off < 256; off <<= 1) {
        int u = (t >= off) ? csum[t - off] : 0;
        __syncthreads();
        csum[t] += u;
        __syncthreads();
    }
    int baseb = (b == 0) ? 0 : csum[b - 1];
    int cntb = csum[b] - baseb;
    if (b == 0 && t == 0) offs[N_NODES] = N_EDGES;
    int n0 = b << 9;
    const int* bp = binned + b * BSEG;
    degl[2 * t] = 0; degl[2 * t + 1] = 0;
    __syncthreads();
    for (int i = t; i < cntb; i += 256) {
        int w = bp[i];
        atomicAdd(&degl[w >> 17], 1);
    }
    __syncthreads();
    int d0 = degl[2 * t], d1 = degl[2 * t + 1];
    int tot = d0 + d1;
    int lane = t & 63, wid = t >> 6;
    int inc = tot;
    #pragma unroll
    for (int off = 1; off < 64; off <<= 1) {
        int v = __shfl_up(inc, off, 64);
        if (lane >= off) inc += v;
    }
    if (lane == 63) wsum[wid] = inc;
    __syncthreads();
    int wb = 0;
    for (int w = 0; w < wid; ++w) wb += wsum[w];
    int excl = wb + inc - tot;
    offl[2 * t] = excl;          curl[2 * t] = excl;
    offl[2 * t + 1] = excl + d0; curl[2 * t + 1] = excl + d0;
    __syncthreads();
    #pragma unroll
    for (int rep = 0; rep < 2; ++rep) {
        int i = t + rep * 256;
        int n = n0 + i;
        if (n < N_NODES) {
            offs[n] = baseb + offl[i];
            float df = (float)degl[i];
            if (df < 1.f) df = 1.f;
            float di = 1.0f / sqrtf(df);
            dinva[n] = di;
            d2a[n] = di * di;
            rda[n] = sqrtf(df);
        }
    }
    for (int i = t; i < cntb; i += 256) {
        int w = bp[i];
        int loc = w >> 17;
        int s = w & 0x1FFFF;
        int p = atomicAdd(&curl[loc], 1);
        if (p < BCAP) adjl[p] = s;
        else adj[baseb + p] = s;
    }
    __syncthreads();
    int lim = cntb < BCAP ? cntb : BCAP;
    for (int i = t; i < lim; i += 256) adj[baseb + i] = adjl[i];
}

// ======= fused MLP via split-bf16 MFMA (fp32-accurate) ======================
// wave = 16 nodes; GEMM1 K=128 (4 ksteps x 4 out-tiles x 3 mfma), h1 via
// wave-private LDS (packed hi|lo), GEMM2 K=64, epilogue -> bf16 gs0.
__global__ __launch_bounds__(256) void k_gemm12(const float* __restrict__ x,
        const unsigned short* __restrict__ w1h, const unsigned short* __restrict__ w1l,
        const unsigned short* __restrict__ w2h, const unsigned short* __restrict__ w2l,
        const float* __restrict__ b1, const float* __restrict__ b2,
        const float* __restrict__ dinva, unsigned short* __restrict__ gsh, int N) {
    __shared__ unsigned int Hl[4][16 * 65];     // packed hi<<16|lo, pad 65
    __shared__ unsigned short Sl[4][16 * 66];   // epilogue staging, pad 66
    int t = threadIdx.x;
    int w = t >> 6, lane = t & 63;
    int c = lane & 15, qd = lane >> 4;
    int nbase = blockIdx.x * 64 + w * 16;
    if (nbase >= N) return;                     // wave-uniform; no block barriers
    int node = nbase + c;
    int nclamp = (node < N) ? node : N - 1;

    f32x4 a0 = {0.f,0.f,0.f,0.f}, a1 = a0, a2 = a0, a3 = a0;
    #pragma unroll
    for (int ks = 0; ks < 4; ++ks) {
        const float* xp = x + (size_t)nclamp * IN_F + ks * 32 + qd * 8;
        float4 xa = *(const float4*)xp;
        float4 xb = *(const float4*)(xp + 4);
        float xs[8] = {xa.x, xa.y, xa.z, xa.w, xb.x, xb.y, xb.z, xb.w};
        bf16x8 ahi, alo;
        #pragma unroll
        for (int j = 0; j < 8; ++j) {
            unsigned short h = bf16rn(xs[j]);
            ahi[j] = (short)h;
            alo[j] = (short)bf16rn(xs[j] - __uint_as_float((unsigned)h << 16));
        }
        const unsigned short* bh = w1h + (size_t)(ks * 4 + qd) * 512;
        const unsigned short* bl = w1l + (size_t)(ks * 4 + qd) * 512;
        bf16x8 h0 = *(const bf16x8*)(bh + 0 * 128 + c * 8);
        bf16x8 l0 = *(const bf16x8*)(bl + 0 * 128 + c * 8);
        bf16x8 h1 = *(const bf16x8*)(bh + 1 * 128 + c * 8);
        bf16x8 l1 = *(const bf16x8*)(bl + 1 * 128 + c * 8);
        bf16x8 h2 = *(const bf16x8*)(bh + 2 * 128 + c * 8);
        bf16x8 l2 = *(const bf16x8*)(bl + 2 * 128 + c * 8);
        bf16x8 h3 = *(const bf16x8*)(bh + 3 * 128 + c * 8);
        bf16x8 l3 = *(const bf16x8*)(bl + 3 * 128 + c * 8);
        a0 = __builtin_amdgcn_mfma_f32_16x16x32_bf16(ahi, h0, a0, 0, 0, 0);
        a1 = __builtin_amdgcn_mfma_f32_16x16x32_bf16(ahi, h1, a1, 0, 0, 0);
        a2 = __builtin_amdgcn_mfma_f32_16x16x32_bf16(ahi, h2, a2, 0, 0, 0);
        a3 = __builtin_amdgcn_mfma_f32_16x16x32_bf16(ahi, h3, a3, 0, 0, 0);
        a0 = __builtin_amdgcn_mfma_f32_16x16x32_bf16(alo, h0, a0, 0, 0, 0);
        a1 = __builtin_amdgcn_mfma_f32_16x16x32_bf16(alo, h1, a1, 0, 0, 0);
        a2 = __builtin_amdgcn_mfma_f32_16x16x32_bf16(alo, h2, a2, 0, 0, 0);
        a3 = __builtin_amdgcn_mfma_f32_16x16x32_bf16(alo, h3, a3, 0, 0, 0);
        a0 = __builtin_amdgcn_mfma_f32_16x16x32_bf16(ahi, l0, a0, 0, 0, 0);
        a1 = __builtin_amdgcn_mfma_f32_16x16x32_bf16(ahi, l1, a1, 0, 0, 0);
        a2 = __builtin_amdgcn_mfma_f32_16x16x32_bf16(ahi, l2, a2, 0, 0, 0);
        a3 = __builtin_amdgcn_mfma_f32_16x16x32_bf16(ahi, l3, a3, 0, 0, 0);
    }
    // h1 = relu(acc + b1) -> LDS packed split (C layout: node=qd*4+r, feat=ot*16+c)
    #pragma unroll
    for (int ot = 0; ot < 4; ++ot) {
        float bb = b1[ot * 16 + c];
        f32x4 a = (ot == 0) ? a0 : (ot == 1) ? a1 : (ot == 2) ? a2 : a3;
        #pragma unroll
        for (int r = 0; r < 4; ++r) {
            float h = fmaxf(a[r] + bb, 0.f);
            unsigned short hh = bf16rn(h);
            unsigned short hl = bf16rn(h - __uint_as_float((unsigned)hh << 16));
            Hl[w][(qd * 4 + r) * 65 + ot * 16 + c] = ((unsigned)hh << 16) | hl;
        }
    }
    // GEMM2: K=64 from LDS
    f32x4 d0 = {0.f,0.f,0.f,0.f}, d1 = d0, d2 = d0, d3 = d0;
    #pragma unroll
    for (int ks = 0; ks < 2; ++ks) {
        bf16x8 ahi, alo;
        #pragma unroll
        for (int j = 0; j < 8; ++j) {
            unsigned v = Hl[w][c * 65 + ks * 32 + qd * 8 + j];
            ahi[j] = (short)(v >> 16);
            alo[j] = (short)(v & 0xFFFFu);
        }
        const unsigned short* bh = w2h + (size_t)(ks * 4 + qd) * 512;
        const unsigned short* bl = w2l + (size_t)(ks * 4 + qd) * 512;
        bf16x8 h0 = *(const bf16x8*)(bh + 0 * 128 + c * 8);
        bf16x8 l0 = *(const bf16x8*)(bl + 0 * 128 + c * 8);
        bf16x8 h1 = *(const bf16x8*)(bh + 1 * 128 + c * 8);
        bf16x8 l1 = *(const bf16x8*)(bl + 1 * 128 + c * 8);
        bf16x8 h2 = *(const bf16x8*)(bh + 2 * 128 + c * 8);
        bf16x8 l2 = *(const bf16x8*)(bl + 2 * 128 + c * 8);
        bf16x8 h3 = *(const bf16x8*)(bh + 3 * 128 + c * 8);
        bf16x8 l3 = *(const bf16x8*)(bl + 3 * 128 + c * 8);
        d0 = __builtin_amdgcn_mfma_f32_16x16x32_bf16(ahi, h0, d0, 0, 0, 0);
        d1 = __builtin_amdgcn_mfma_f32_16x16x32_bf16(ahi, h1, d1, 0, 0, 0);
        d2 = __builtin_amdgcn_mfma_f32_16x16x32_bf16(ahi, h2, d2, 0, 0, 0);
        d3 = __builtin_amdgcn_mfma_f32_16x16x32_bf16(ahi, h3, d3, 0, 0, 0);
        d0 = __builtin_amdgcn_mfma_f32_16x16x32_bf16(alo, h0, d0, 0, 0, 0);
        d1 = __builtin_amdgcn_mfma_f32_16x16x32_bf16(alo, h1, d1, 0, 0, 0);
        d2 = __builtin_amdgcn_mfma_f32_16x16x32_bf16(alo, h2, d2, 0, 0, 0);
        d3 = __builtin_amdgcn_mfma_f32_16x16x32_bf16(alo, h3, d3, 0, 0, 0);
        d0 = __builtin_amdgcn_mfma_f32_16x16x32_bf16(ahi, l0, d0, 0, 0, 0);
        d1 = __builtin_amdgcn_mfma_f32_16x16x32_bf16(ahi, l1, d1, 0, 0, 0);
        d2 = __builtin_amdgcn_mfma_f32_16x16x32_bf16(ahi, l2, d2, 0, 0, 0);
        d3 = __builtin_amdgcn_mfma_f32_16x16x32_bf16(ahi, l3, d3, 0, 0, 0);
    }
    // epilogue: gs0 = bf16(dinv * relu(acc + b2)) -> LDS -> coalesced dump
    #pragma unroll
    for (int ot = 0; ot < 4; ++ot) {
        float bb = b2[ot * 16 + c];
        f32x4 a = (ot == 0) ? d0 : (ot == 1) ? d1 : (ot == 2) ? d2 : d3;
        #pragma unroll
        for (int r = 0; r < 4; ++r) {
            int nd = nbase + qd * 4 + r;
            float di = dinva[(nd < N) ? nd : N - 1];
            Sl[w][(qd * 4 + r) * 66 + ot * 16 + c] = bf16rn(di * fmaxf(a[r] + bb, 0.f));
        }
    }
    #pragma unroll
    for (int i = 0; i < 4; ++i) {
        int nl = i * 4 + qd;
        int nd = nbase + nl;
        if (nd < N) {
            ushort4 v;
            v.x = Sl[w][nl * 66 + c * 4 + 0];
            v.y = Sl[w][nl * 66 + c * 4 + 1];
            v.z = Sl[w][nl * 66 + c * 4 + 2];
            v.w = Sl[w][nl * 66 + c * 4 + 3];
            *(ushort4*)(gsh + (size_t)nd * 64 + c * 4) = v;
        }
    }
}

// ---- propagation (bf16 -> bf16): gout = gin - d2[n]*sum_src gin[src] ----
__global__ __launch_bounds__(256) void k_prop(const unsigned short* __restrict__ gh,
        unsigned short* __restrict__ gout, const int* __restrict__ offs,
        const int* __restrict__ adj, const float* __restrict__ d2a, int N) {
    int t = threadIdx.x;
    int lane = t & 63;
    int g = lane >> 3;
    int q = lane & 7;
    int n = blockIdx.x * 4 + (t >> 6);
    if (n >= N) return;
    int beg = offs[n], end = offs[n + 1];
    float a0 = 0.f, a1 = 0.f, a2 = 0.f, a3 = 0.f;
    float a4 = 0.f, a5 = 0.f, a6 = 0.f, a7 = 0.f;
    int e = beg + g;
    for (; e + 24 < end; e += 32) {
        int s0 = adj[e], s1 = adj[e + 8], s2 = adj[e + 16], s3 = adj[e + 24];
        uint4 v0 = *(const uint4*)(gh + (size_t)s0 * 64 + 8 * q);
        uint4 v1 = *(const uint4*)(gh + (size_t)s1 * 64 + 8 * q);
        uint4 v2 = *(const uint4*)(gh + (size_t)s2 * 64 + 8 * q);
        uint4 v3 = *(const uint4*)(gh + (size_t)s3 * 64 + 8 * q);
        float l, h;
        UNPK(v0.x, l, h); a0 += l; a1 += h;
        UNPK(v0.y, l, h); a2 += l; a3 += h;
        UNPK(v0.z, l, h); a4 += l; a5 += h;
        UNPK(v0.w, l, h); a6 += l; a7 += h;
        UNPK(v1.x, l, h); a0 += l; a1 += h;
        UNPK(v1.y, l, h); a2 += l; a3 += h;
        UNPK(v1.z, l, h); a4 += l; a5 += h;
        UNPK(v1.w, l, h); a6 += l; a7 += h;
        UNPK(v2.x, l, h); a0 += l; a1 += h;
        UNPK(v2.y, l, h); a2 += l; a3 += h;
        UNPK(v2.z, l, h); a4 += l; a5 += h;
        UNPK(v2.w, l, h); a6 += l; a7 += h;
        UNPK(v3.x, l, h); a0 += l; a1 += h;
        UNPK(v3.y, l, h); a2 += l; a3 += h;
        UNPK(v3.z, l, h); a4 += l; a5 += h;
        UNPK(v3.w, l, h); a6 += l; a7 += h;
    }
    for (; e < end; e += 8) {
        int s = adj[e];
        uint4 v = *(const uint4*)(gh + (size_t)s * 64 + 8 * q);
        float l, h;
        UNPK(v.x, l, h); a0 += l; a1 += h;
        UNPK(v.y, l, h); a2 += l; a3 += h;
        UNPK(v.z, l, h); a4 += l; a5 += h;
        UNPK(v.w, l, h); a6 += l; a7 += h;
    }
    #pragma unroll
    for (int m = 8; m < 64; m <<= 1) {
        a0 += __shfl_xor(a0, m); a1 += __shfl_xor(a1, m);
        a2 += __shfl_xor(a2, m); a3 += __shfl_xor(a3, m);
        a4 += __shfl_xor(a4, m); a5 += __shfl_xor(a5, m);
        a6 += __shfl_xor(a6, m); a7 += __shfl_xor(a7, m);
    }
    if (g == 0) {
        float d2n = d2a[n];
        uint4 sv = *(const uint4*)(gh + (size_t)n * 64 + 8 * q);
        float l, h;
        uint4 r;
        UNPK(sv.x, l, h);
        r.x = ((unsigned)bf16rn(fmaf(-d2n, a1, h)) << 16) | bf16rn(fmaf(-d2n, a0, l));
        UNPK(sv.y, l, h);
        r.y = ((unsigned)bf16rn(fmaf(-d2n, a3, h)) << 16) | bf16rn(fmaf(-d2n, a2, l));
        UNPK(sv.z, l, h);
        r.z = ((unsigned)bf16rn(fmaf(-d2n, a5, h)) << 16) | bf16rn(fmaf(-d2n, a4, l));
        UNPK(sv.w, l, h);
        r.w = ((unsigned)bf16rn(fmaf(-d2n, a7, h)) << 16) | bf16rn(fmaf(-d2n, a6, l));
        *(uint4*)(gout + (size_t)n * 64 + 8 * q) = r;
    }
}

// ---- MFMA head: wave = 16 nodes x 64 outs, K=192 over 3 bf16 slices ----
__global__ __launch_bounds__(256) void k_final(const unsigned short* __restrict__ g0h,
        const unsigned short* __restrict__ g1h, const unsigned short* __restrict__ g2h,
        const unsigned short* __restrict__ mpk, const float* __restrict__ bm1,
        const float* __restrict__ Wm2, const float* __restrict__ bm2,
        const float* __restrict__ rda, float* __restrict__ out, int N) {
    int t = threadIdx.x;
    int w = t >> 6, lane = t & 63;
    int c = lane & 15, qd = lane >> 4;
    int nbase = blockIdx.x * 64 + w * 16;
    if (nbase >= N) return;
    int node = nbase + c;
    int nclamp = (node < N) ? node : N - 1;
    const unsigned short* bufs[3] = {g0h, g1h, g2h};
    f32x4 acc0 = {0.f, 0.f, 0.f, 0.f};
    f32x4 acc1 = {0.f, 0.f, 0.f, 0.f};
    f32x4 acc2 = {0.f, 0.f, 0.f, 0.f};
    f32x4 acc3 = {0.f, 0.f, 0.f, 0.f};
    #pragma unroll
    for (int s = 0; s < 6; ++s) {
        const unsigned short* gp = bufs[s >> 1];
        int k0 = (s & 1) * 32;
        bf16x8 a = *(const bf16x8*)(gp + (size_t)nclamp * 64 + k0 + qd * 8);
        const unsigned short* mb = mpk + (size_t)((s * 4 + qd) * 64) * 8;
        bf16x8 b0 = *(const bf16x8*)(mb + (size_t)(c) * 8);
        bf16x8 b1 = *(const bf16x8*)(mb + (size_t)(16 + c) * 8);
        bf16x8 b2 = *(const bf16x8*)(mb + (size_t)(32 + c) * 8);
        bf16x8 b3 = *(const bf16x8*)(mb + (size_t)(48 + c) * 8);
        acc0 = __builtin_amdgcn_mfma_f32_16x16x32_bf16(a, b0, acc0, 0, 0, 0);
        acc1 = __builtin_amdgcn_mfma_f32_16x16x32_bf16(a, b1, acc1, 0, 0, 0);
        acc2 = __builtin_amdgcn_mfma_f32_16x16x32_bf16(a, b2, acc2, 0, 0, 0);
        acc3 = __builtin_amdgcn_mfma_f32_16x16x32_bf16(a, b3, acc3, 0, 0, 0);
    }
    float rdr[4];
    #pragma unroll
    for (int r = 0; r < 4; ++r) {
        int nd = nbase + qd * 4 + r;
        rdr[r] = rda[(nd < N) ? nd : N - 1];
    }
    float p0[4] = {0.f, 0.f, 0.f, 0.f};
    float p1[4] = {0.f, 0.f, 0.f, 0.f};
    #pragma unroll
    for (int ot = 0; ot < 4; ++ot) {
        int col = ot * 16 + c;
        float bmc = bm1[col];
        float wc0 = Wm2[col * 2 + 0];
        float wc1 = Wm2[col * 2 + 1];
        f32x4 a = (ot == 0) ? acc0 : (ot == 1) ? acc1 : (ot == 2) ? acc2 : acc3;
        #pragma unroll
        for (int r = 0; r < 4; ++r) {
            float h = fmaxf(fmaf(rdr[r], a[r], bmc), 0.f);
            p0[r] = fmaf(h, wc0, p0[r]);
            p1[r] = fmaf(h, wc1, p1[r]);
        }
    }
    #pragma unroll
    for (int m = 1; m < 16; m <<= 1) {
        #pragma unroll
        for (int r = 0; r < 4; ++r) {
            p0[r] += __shfl_xor(p0[r], m);
            p1[r] += __shfl_xor(p1[r], m);
        }
    }
    if (c == 0) {
        float bo0 = bm2[0], bo1 = bm2[1];
        #pragma unroll
        for (int r = 0; r < 4; ++r) {
            int nd = nbase + qd * 4 + r;
            if (nd < N) {
                float2 o;
                o.x = p0[r] + bo0;
                o.y = p1[r] + bo1;
                *(float2*)(out + (size_t)nd * 2) = o;
            }
        }
    }
}

extern "C" void kernel_launch(void* const* d_in, const int* in_sizes, int n_in,
                              void* d_out, int out_size, void* d_ws, size_t ws_size,
                              hipStream_t stream) {
    const float* x   = (const float*)d_in[0];
    const int*   ei  = (const int*)d_in[1];
    const float* W1  = (const float*)d_in[2];
    const float* b1  = (const float*)d_in[3];
    const float* W2  = (const float*)d_in[4];
    const float* b2  = (const float*)d_in[5];
    const float* Wm1 = (const float*)d_in[6];
    const float* bm1 = (const float*)d_in[7];
    const float* Wm2 = (const float*)d_in[8];
    const float* bm2 = (const float*)d_in[9];
    float* out = (float*)d_out;

    int* ws = (int*)d_ws;
    int*   cnt   = ws + OFF_CNT;
    unsigned short* mpk = (unsigned short*)(ws + OFF_MPK);
    unsigned short* w1h = (unsigned short*)(ws + OFF_W1H);
    unsigned short* w1l = (unsigned short*)(ws + OFF_W1L);
    unsigned short* w2h = (unsigned short*)(ws + OFF_W2H);
    unsigned short* w2l = (unsigned short*)(ws + OFF_W2L);
    int*   offs  = ws + OFF_OFFS;
    float* d2a   = (float*)(ws + OFF_D2);
    float* rda   = (float*)(ws + OFF_RD);
    float* dinva = (float*)(ws + OFF_DINV);
    int*   adj   = ws + OFF_ADJ;
    unsigned short* gs0h = (unsigned short*)(ws + OFF_H0);
    unsigned short* gs1h = (unsigned short*)(ws + OFF_H1);
    unsigned short* gs2h = (unsigned short*)(ws + OFF_H2);
    int*   binned = ws + OFF_H1;   // aliases H1(+H2); dead before prop1 writes gs1h

    const int* srcp = ei;
    const int* dstp = ei + N_EDGES;

    hipMemsetAsync(cnt, 0, 256 * sizeof(int), stream);

    k_prep<<<96, 256, 0, stream>>>(Wm1, W1, W2, mpk, w1h, w1l, w2h, w2l);
    k_bin<<<(N_EDGES + 4095) / 4096, 256, 0, stream>>>(srcp, dstp, cnt, binned, N_EDGES);
    k_cfill<<<NBKT, 256, 0, stream>>>(binned, cnt, offs, adj, d2a, rda, dinva);

    int nblk = (N_NODES + 63) / 64;
    k_gemm12<<<nblk, 256, 0, stream>>>(x, w1h, w1l, w2h, w2l, b1, b2, dinva, gs0h, N_NODES);

    k_prop<<<(N_NODES + 3) / 4, 256, 0, stream>>>(gs0h, gs1h, offs, adj, d2a, N_NODES);
    k_prop<<<(N_NODES + 3) / 4, 256, 0, stream>>>(gs1h, gs2h, offs, adj, d2a, N_NODES);

    k_final<<<nblk, 256, 0, stream>>>(gs0h, gs1h, gs2h, mpk, bm1, Wm2, bm2, rda, out, N_NODES);
}

// Round 10
// 254.170 us; speedup vs baseline: 1.5900x; 1.0628x over previous
//
#include <hip/hip_runtime.h>
#include <math.h>

#define N_NODES 100000
#define N_EDGES 1600000
#define IN_F 128
#define H_F 64

#define NBKT 391     // ceil(100000/256) buckets of 256 nodes
#define BSEG 5120    // per-bucket segment capacity (mean 4092, sigma 64)
#define BCAP 5120    // LDS staging capacity for adj per bucket (20KB)

// workspace layout in 4-byte words (~46.5 MB total)
#define NP        100096
#define OFF_CNT   0                           // int[512]
#define OFF_MPK   512                         // ushort[12288] packed bf16 Mcat
#define OFF_W1H   6656                        // ushort[8192] W1 hi, B-frag order
#define OFF_W1L   10752                       // ushort[8192] W1 lo
#define OFF_W2H   14848                       // ushort[4096] W2 hi
#define OFF_W2L   16896                       // ushort[4096] W2 lo
#define OFF_OFFS  18944                       // int[N+1]
#define OFF_D2    (OFF_OFFS + NP + 64)        // float[NP]
#define OFF_RD    (OFF_D2 + NP)               // float[NP]
#define OFF_DINV  (OFF_RD + NP)               // float[NP]
#define OFF_ADJ   (OFF_DINV + NP)             // int[N_EDGES]
#define OFF_H0    (OFF_ADJ + N_EDGES)         // ushort[N*64] bf16 gs0
#define OFF_H1    (OFF_H0 + N_NODES*32)       // ushort[N*64] bf16 gs1; binned aliases H1+H2
#define OFF_H2    (OFF_H1 + N_NODES*32)       // ushort[N*64] bf16 gs2

typedef __attribute__((ext_vector_type(8))) short bf16x8;
typedef __attribute__((ext_vector_type(4))) float f32x4;

__device__ __forceinline__ unsigned short bf16rn(float f) {
    unsigned u = __float_as_uint(f);
    u += 0x7FFFu + ((u >> 16) & 1u);
    return (unsigned short)(u >> 16);
}
#define UNPK(u, lo, hi) { lo = __uint_as_float((u) << 16); hi = __uint_as_float((u) & 0xFFFF0000u); }

// ---- prep: zero cnt; pack Mcat + split-bf16 W1/W2 B-fragments ----
__global__ __launch_bounds__(256) void k_prep(const float* __restrict__ Wm1,
        const float* __restrict__ W1, const float* __restrict__ W2,
        unsigned short* __restrict__ mpk,
        unsigned short* __restrict__ w1h, unsigned short* __restrict__ w1l,
        unsigned short* __restrict__ w2h, unsigned short* __restrict__ w2l,
        int* __restrict__ cnt) {
    int idx = blockIdx.x * 256 + threadIdx.x;
    if (idx < 512) cnt[idx] = 0;
    if (idx < 12288) {
        int j = idx & 7;
        int n = (idx >> 3) & 63;
        int qd = (idx >> 9) & 3;
        int s = idx >> 11;
        int k = s * 32 + qd * 8 + j;
        int p = k >> 6;
        int kk = k & 63;
        float w0 = Wm1[kk * 64 + n];
        float w1 = Wm1[(64 + kk) * 64 + n];
        float w2 = Wm1[(128 + kk) * 64 + n];
        float v;
        if (p == 0)      v = 3.0f * w0;
        else if (p == 1) v = 3.0f * (w1 - w0);
        else             v = 0.75f * (w0 + w2) - 1.5f * w1;
        mpk[idx] = bf16rn(v);
    } else if (idx < 12288 + 8192) {
        int lin = idx - 12288;
        int j = lin & 7, cc = (lin >> 3) & 15, ot = (lin >> 7) & 3;
        int qd = (lin >> 9) & 3, ks = lin >> 11;
        float v = W1[(ks * 32 + qd * 8 + j) * 64 + ot * 16 + cc];
        unsigned short h = bf16rn(v);
        w1h[lin] = h;
        w1l[lin] = bf16rn(v - __uint_as_float((unsigned)h << 16));
    } else if (idx < 24576) {
        int lin = idx - 20480;
        int j = lin & 7, cc = (lin >> 3) & 15, ot = (lin >> 7) & 3;
        int qd = (lin >> 9) & 3, ks = lin >> 11;
        float v = W2[(ks * 32 + qd * 8 + j) * 64 + ot * 16 + cc];
        unsigned short h = bf16rn(v);
        w2h[lin] = h;
        w2l[lin] = bf16rn(v - __uint_as_float((unsigned)h << 16));
    }
}

// ---- pass A: bin edges by dst>>8, per-wave histograms + sub-range reserve ----
__global__ __launch_bounds__(256) void k_bin(const int* __restrict__ src,
        const int* __restrict__ dst, int* __restrict__ cnt,
        int* __restrict__ binned, int E) {
    __shared__ int hist[4][NBKT + 1];
    __shared__ int cur4[4][NBKT + 1];
    int t = threadIdx.x;
    int w = t >> 6;
    for (int i = t; i < 4 * (NBKT + 1); i += 256) (&hist[0][0])[i] = 0;
    __syncthreads();
    int base = blockIdx.x * 2048 + t;
    int d[8];
    #pragma unroll
    for (int i = 0; i < 8; ++i) {
        int e = base + i * 256;
        int dd = (e < E) ? dst[e] : -1;
        d[i] = dd;
        if (dd >= 0) atomicAdd(&hist[w][dd >> 8], 1);
    }
    __syncthreads();
    for (int i = t; i < NBKT; i += 256) {
        int h0 = hist[0][i], h1 = hist[1][i], h2 = hist[2][i], h3 = hist[3][i];
        int tot = h0 + h1 + h2 + h3;
        int b0 = (tot > 0) ? atomicAdd(&cnt[i], tot) : 0;
        cur4[0][i] = b0;
        cur4[1][i] = b0 + h0;
        cur4[2][i] = b0 + h0 + h1;
        cur4[3][i] = b0 + h0 + h1 + h2;
    }
    __syncthreads();
    #pragma unroll
    for (int i = 0; i < 8; ++i) {
        int e = base + i * 256;
        if (e < E) {
            int s = src[e];
            int dd = d[i];
            int b = dd >> 8;
            int p = atomicAdd(&cur4[w][b], 1);
            if (p < BSEG) binned[b * BSEG + p] = ((dd & 255) << 17) | s;
        }
    }
}

// ---- pass B: per-bucket CSR fill (256 nodes/bucket) ----
__global__ __launch_bounds__(256) void k_cfill(const int* __restrict__ binned,
        const int* __restrict__ cnt, int* __restrict__ offs, int* __restrict__ adj,
        float* __restrict__ d2a, float* __restrict__ rda, float* __restrict__ dinva) {
    __shared__ int csum[256];
    __shared__ int degl[256];
    __shared__ int curl[256];
    __shared__ int wsum[4];
    __shared__ int adjl[BCAP];
    int b = blockIdx.x, t = threadIdx.x;
    // pair-sum scan of bucket counts -> baseb
    int p = 0;
    if (2 * t < NBKT) p += cnt[2 * t];
    if (2 * t + 1 < NBKT) p += cnt[2 * t + 1];
    csum[t] = p;
    __syncthreads();
    #pragma unroll
    for (int off = 1; off < 256; off <<= 1) {
        int u = (t >= off) ? csum[t - off] : 0;
        __syncthreads();
        csum[t] += u;
        __syncthreads();
    }
    int b2 = b >> 1;
    int baseb = ((b2 > 0) ? csum[b2 - 1] : 0) + ((b & 1) ? cnt[b - 1] : 0);
    int cntb = cnt[b];
    if (b == 0 && t == 0) offs[N_NODES] = N_EDGES;
    int n0 = b << 8;
    const int* bp = binned + b * BSEG;
    degl[t] = 0;
    __syncthreads();
    for (int i = t; i < cntb; i += 256) atomicAdd(&degl[bp[i] >> 17], 1);
    __syncthreads();
    int d0 = degl[t];
    int lane = t & 63, wid = t >> 6;
    int inc = d0;
    #pragma unroll
    for (int off = 1; off < 64; off <<= 1) {
        int v = __shfl_up(inc, off, 64);
        if (lane >= off) inc += v;
    }
    if (lane == 63) wsum[wid] = inc;
    __syncthreads();
    int wb = 0;
    for (int w = 0; w < wid; ++w) wb += wsum[w];
    int excl = wb + inc - d0;
    curl[t] = excl;
    int n = n0 + t;
    if (n < N_NODES) {
        offs[n] = baseb + excl;
        float df = (float)d0;
        if (df < 1.f) df = 1.f;
        float di = 1.0f / sqrtf(df);
        dinva[n] = di;
        d2a[n] = di * di;
        rda[n] = sqrtf(df);
    }
    __syncthreads();
    for (int i = t; i < cntb; i += 256) {
        int w = bp[i];
        int loc = w >> 17;
        int s = w & 0x1FFFF;
        int pp = atomicAdd(&curl[loc], 1);
        if (pp < BCAP) adjl[pp] = s;
        else adj[baseb + pp] = s;
    }
    __syncthreads();
    int lim = cntb < BCAP ? cntb : BCAP;
    for (int i = t; i < lim; i += 256) adj[baseb + i] = adjl[i];
}

// ======= fused MLP via split-bf16 MFMA (fp32-accurate) ======================
__global__ __launch_bounds__(256) void k_gemm12(const float* __restrict__ x,
        const unsigned short* __restrict__ w1h, const unsigned short* __restrict__ w1l,
        const unsigned short* __restrict__ w2h, const unsigned short* __restrict__ w2l,
        const float* __restrict__ b1, const float* __restrict__ b2,
        const float* __restrict__ dinva, unsigned short* __restrict__ gsh, int N) {
    __shared__ unsigned int Hl[4][16 * 65];
    __shared__ unsigned short Sl[4][16 * 66];
    int t = threadIdx.x;
    int w = t >> 6, lane = t & 63;
    int c = lane & 15, qd = lane >> 4;
    int nbase = blockIdx.x * 64 + w * 16;
    if (nbase >= N) return;
    int node = nbase + c;
    int nclamp = (node < N) ? node : N - 1;

    f32x4 a0 = {0.f,0.f,0.f,0.f}, a1 = a0, a2 = a0, a3 = a0;
    #pragma unroll
    for (int ks = 0; ks < 4; ++ks) {
        const float* xp = x + (size_t)nclamp * IN_F + ks * 32 + qd * 8;
        float4 xa = *(const float4*)xp;
        float4 xb = *(const float4*)(xp + 4);
        float xs[8] = {xa.x, xa.y, xa.z, xa.w, xb.x, xb.y, xb.z, xb.w};
        bf16x8 ahi, alo;
        #pragma unroll
        for (int j = 0; j < 8; ++j) {
            unsigned short h = bf16rn(xs[j]);
            ahi[j] = (short)h;
            alo[j] = (short)bf16rn(xs[j] - __uint_as_float((unsigned)h << 16));
        }
        const unsigned short* bh = w1h + (size_t)(ks * 4 + qd) * 512;
        const unsigned short* bl = w1l + (size_t)(ks * 4 + qd) * 512;
        bf16x8 h0 = *(const bf16x8*)(bh + 0 * 128 + c * 8);
        bf16x8 l0 = *(const bf16x8*)(bl + 0 * 128 + c * 8);
        bf16x8 h1 = *(const bf16x8*)(bh + 1 * 128 + c * 8);
        bf16x8 l1 = *(const bf16x8*)(bl + 1 * 128 + c * 8);
        bf16x8 h2 = *(const bf16x8*)(bh + 2 * 128 + c * 8);
        bf16x8 l2 = *(const bf16x8*)(bl + 2 * 128 + c * 8);
        bf16x8 h3 = *(const bf16x8*)(bh + 3 * 128 + c * 8);
        bf16x8 l3 = *(const bf16x8*)(bl + 3 * 128 + c * 8);
        a0 = __builtin_amdgcn_mfma_f32_16x16x32_bf16(ahi, h0, a0, 0, 0, 0);
        a1 = __builtin_amdgcn_mfma_f32_16x16x32_bf16(ahi, h1, a1, 0, 0, 0);
        a2 = __builtin_amdgcn_mfma_f32_16x16x32_bf16(ahi, h2, a2, 0, 0, 0);
        a3 = __builtin_amdgcn_mfma_f32_16x16x32_bf16(ahi, h3, a3, 0, 0, 0);
        a0 = __builtin_amdgcn_mfma_f32_16x16x32_bf16(alo, h0, a0, 0, 0, 0);
        a1 = __builtin_amdgcn_mfma_f32_16x16x32_bf16(alo, h1, a1, 0, 0, 0);
        a2 = __builtin_amdgcn_mfma_f32_16x16x32_bf16(alo, h2, a2, 0, 0, 0);
        a3 = __builtin_amdgcn_mfma_f32_16x16x32_bf16(alo, h3, a3, 0, 0, 0);
        a0 = __builtin_amdgcn_mfma_f32_16x16x32_bf16(ahi, l0, a0, 0, 0, 0);
        a1 = __builtin_amdgcn_mfma_f32_16x16x32_bf16(ahi, l1, a1, 0, 0, 0);
        a2 = __builtin_amdgcn_mfma_f32_16x16x32_bf16(ahi, l2, a2, 0, 0, 0);
        a3 = __builtin_amdgcn_mfma_f32_16x16x32_bf16(ahi, l3, a3, 0, 0, 0);
    }
    #pragma unroll
    for (int ot = 0; ot < 4; ++ot) {
        float bb = b1[ot * 16 + c];
        f32x4 a = (ot == 0) ? a0 : (ot == 1) ? a1 : (ot == 2) ? a2 : a3;
        #pragma unroll
        for (int r = 0; r < 4; ++r) {
            float h = fmaxf(a[r] + bb, 0.f);
            unsigned short hh = bf16rn(h);
            unsigned short hl = bf16rn(h - __uint_as_float((unsigned)hh << 16));
            Hl[w][(qd * 4 + r) * 65 + ot * 16 + c] = ((unsigned)hh << 16) | hl;
        }
    }
    f32x4 d0 = {0.f,0.f,0.f,0.f}, d1 = d0, d2 = d0, d3 = d0;
    #pragma unroll
    for (int ks = 0; ks < 2; ++ks) {
        bf16x8 ahi, alo;
        #pragma unroll
        for (int j = 0; j < 8; ++j) {
            unsigned v = Hl[w][c * 65 + ks * 32 + qd * 8 + j];
            ahi[j] = (short)(v >> 16);
            alo[j] = (short)(v & 0xFFFFu);
        }
        const unsigned short* bh = w2h + (size_t)(ks * 4 + qd) * 512;
        const unsigned short* bl = w2l + (size_t)(ks * 4 + qd) * 512;
        bf16x8 h0 = *(const bf16x8*)(bh + 0 * 128 + c * 8);
        bf16x8 l0 = *(const bf16x8*)(bl + 0 * 128 + c * 8);
        bf16x8 h1 = *(const bf16x8*)(bh + 1 * 128 + c * 8);
        bf16x8 l1 = *(const bf16x8*)(bl + 1 * 128 + c * 8);
        bf16x8 h2 = *(const bf16x8*)(bh + 2 * 128 + c * 8);
        bf16x8 l2 = *(const bf16x8*)(bl + 2 * 128 + c * 8);
        bf16x8 h3 = *(const bf16x8*)(bh + 3 * 128 + c * 8);
        bf16x8 l3 = *(const bf16x8*)(bl + 3 * 128 + c * 8);
        d0 = __builtin_amdgcn_mfma_f32_16x16x32_bf16(ahi, h0, d0, 0, 0, 0);
        d1 = __builtin_amdgcn_mfma_f32_16x16x32_bf16(ahi, h1, d1, 0, 0, 0);
        d2 = __builtin_amdgcn_mfma_f32_16x16x32_bf16(ahi, h2, d2, 0, 0, 0);
        d3 = __builtin_amdgcn_mfma_f32_16x16x32_bf16(ahi, h3, d3, 0, 0, 0);
        d0 = __builtin_amdgcn_mfma_f32_16x16x32_bf16(alo, h0, d0, 0, 0, 0);
        d1 = __builtin_amdgcn_mfma_f32_16x16x32_bf16(alo, h1, d1, 0, 0, 0);
        d2 = __builtin_amdgcn_mfma_f32_16x16x32_bf16(alo, h2, d2, 0, 0, 0);
        d3 = __builtin_amdgcn_mfma_f32_16x16x32_bf16(alo, h3, d3, 0, 0, 0);
        d0 = __builtin_amdgcn_mfma_f32_16x16x32_bf16(ahi, l0, d0, 0, 0, 0);
        d1 = __builtin_amdgcn_mfma_f32_16x16x32_bf16(ahi, l1, d1, 0, 0, 0);
        d2 = __builtin_amdgcn_mfma_f32_16x16x32_bf16(ahi, l2, d2, 0, 0, 0);
        d3 = __builtin_amdgcn_mfma_f32_16x16x32_bf16(ahi, l3, d3, 0, 0, 0);
    }
    #pragma unroll
    for (int ot = 0; ot < 4; ++ot) {
        float bb = b2[ot * 16 + c];
        f32x4 a = (ot == 0) ? d0 : (ot == 1) ? d1 : (ot == 2) ? d2 : d3;
        #pragma unroll
        for (int r = 0; r < 4; ++r) {
            int nd = nbase + qd * 4 + r;
            float di = dinva[(nd < N) ? nd : N - 1];
            Sl[w][(qd * 4 + r) * 66 + ot * 16 + c] = bf16rn(di * fmaxf(a[r] + bb, 0.f));
        }
    }
    #pragma unroll
    for (int i = 0; i < 4; ++i) {
        int nl = i * 4 + qd;
        int nd = nbase + nl;
        if (nd < N) {
            ushort4 v;
            v.x = Sl[w][nl * 66 + c * 4 + 0];
            v.y = Sl[w][nl * 66 + c * 4 + 1];
            v.z = Sl[w][nl * 66 + c * 4 + 2];
            v.w = Sl[w][nl * 66 + c * 4 + 3];
            *(ushort4*)(gsh + (size_t)nd * 64 + c * 4) = v;
        }
    }
}

// ---- propagation (bf16 -> bf16), 1-ahead software pipeline ----
__global__ __launch_bounds__(256) void k_prop(const unsigned short* __restrict__ gh,
        unsigned short* __restrict__ gout, const int* __restrict__ offs,
        const int* __restrict__ adj, const float* __restrict__ d2a, int N) {
    int t = threadIdx.x;
    int lane = t & 63;
    int g = lane >> 3;
    int q = lane & 7;
    int n = blockIdx.x * 4 + (t >> 6);
    if (n >= N) return;
    int beg = offs[n], end = offs[n + 1];
    float d2n = d2a[n];                                        // early
    uint4 sv = *(const uint4*)(gh + (size_t)n * 64 + 8 * q);   // early self (broadcast line)
    float a0 = 0.f, a1 = 0.f, a2 = 0.f, a3 = 0.f;
    float a4 = 0.f, a5 = 0.f, a6 = 0.f, a7 = 0.f;
    int e = beg + g;
    if (e < end) {
        int s = adj[e];
        uint4 v = *(const uint4*)(gh + (size_t)s * 64 + 8 * q);
        for (e += 8; e < end; e += 8) {
            int s2 = adj[e];
            uint4 v2 = *(const uint4*)(gh + (size_t)s2 * 64 + 8 * q);
            float l, h;
            UNPK(v.x, l, h); a0 += l; a1 += h;
            UNPK(v.y, l, h); a2 += l; a3 += h;
            UNPK(v.z, l, h); a4 += l; a5 += h;
            UNPK(v.w, l, h); a6 += l; a7 += h;
            v = v2;
        }
        float l, h;
        UNPK(v.x, l, h); a0 += l; a1 += h;
        UNPK(v.y, l, h); a2 += l; a3 += h;
        UNPK(v.z, l, h); a4 += l; a5 += h;
        UNPK(v.w, l, h); a6 += l; a7 += h;
    }
    #pragma unroll
    for (int m = 8; m < 64; m <<= 1) {
        a0 += __shfl_xor(a0, m); a1 += __shfl_xor(a1, m);
        a2 += __shfl_xor(a2, m); a3 += __shfl_xor(a3, m);
        a4 += __shfl_xor(a4, m); a5 += __shfl_xor(a5, m);
        a6 += __shfl_xor(a6, m); a7 += __shfl_xor(a7, m);
    }
    if (g == 0) {
        float l, h;
        uint4 r;
        UNPK(sv.x, l, h);
        r.x = ((unsigned)bf16rn(fmaf(-d2n, a1, h)) << 16) | bf16rn(fmaf(-d2n, a0, l));
        UNPK(sv.y, l, h);
        r.y = ((unsigned)bf16rn(fmaf(-d2n, a3, h)) << 16) | bf16rn(fmaf(-d2n, a2, l));
        UNPK(sv.z, l, h);
        r.z = ((unsigned)bf16rn(fmaf(-d2n, a5, h)) << 16) | bf16rn(fmaf(-d2n, a4, l));
        UNPK(sv.w, l, h);
        r.w = ((unsigned)bf16rn(fmaf(-d2n, a7, h)) << 16) | bf16rn(fmaf(-d2n, a6, l));
        *(uint4*)(gout + (size_t)n * 64 + 8 * q) = r;
    }
}

// ---- MFMA head: wave = 16 nodes x 64 outs, K=192 over 3 bf16 slices ----
__global__ __launch_bounds__(256) void k_final(const unsigned short* __restrict__ g0h,
        const unsigned short* __restrict__ g1h, const unsigned short* __restrict__ g2h,
        const unsigned short* __restrict__ mpk, const float* __restrict__ bm1,
        const float* __restrict__ Wm2, const float* __restrict__ bm2,
        const float* __restrict__ rda, float* __restrict__ out, int N) {
    int t = threadIdx.x;
    int w = t >> 6, lane = t & 63;
    int c = lane & 15, qd = lane >> 4;
    int nbase = blockIdx.x * 64 + w * 16;
    if (nbase >= N) return;
    int node = nbase + c;
    int nclamp = (node < N) ? node : N - 1;
    const unsigned short* bufs[3] = {g0h, g1h, g2h};
    f32x4 acc0 = {0.f, 0.f, 0.f, 0.f};
    f32x4 acc1 = {0.f, 0.f, 0.f, 0.f};
    f32x4 acc2 = {0.f, 0.f, 0.f, 0.f};
    f32x4 acc3 = {0.f, 0.f, 0.f, 0.f};
    #pragma unroll
    for (int s = 0; s < 6; ++s) {
        const unsigned short* gp = bufs[s >> 1];
        int k0 = (s & 1) * 32;
        bf16x8 a = *(const bf16x8*)(gp + (size_t)nclamp * 64 + k0 + qd * 8);
        const unsigned short* mb = mpk + (size_t)((s * 4 + qd) * 64) * 8;
        bf16x8 b0 = *(const bf16x8*)(mb + (size_t)(c) * 8);
        bf16x8 b1 = *(const bf16x8*)(mb + (size_t)(16 + c) * 8);
        bf16x8 b2 = *(const bf16x8*)(mb + (size_t)(32 + c) * 8);
        bf16x8 b3 = *(const bf16x8*)(mb + (size_t)(48 + c) * 8);
        acc0 = __builtin_amdgcn_mfma_f32_16x16x32_bf16(a, b0, acc0, 0, 0, 0);
        acc1 = __builtin_amdgcn_mfma_f32_16x16x32_bf16(a, b1, acc1, 0, 0, 0);
        acc2 = __builtin_amdgcn_mfma_f32_16x16x32_bf16(a, b2, acc2, 0, 0, 0);
        acc3 = __builtin_amdgcn_mfma_f32_16x16x32_bf16(a, b3, acc3, 0, 0, 0);
    }
    float rdr[4];
    #pragma unroll
    for (int r = 0; r < 4; ++r) {
        int nd = nbase + qd * 4 + r;
        rdr[r] = rda[(nd < N) ? nd : N - 1];
    }
    float p0[4] = {0.f, 0.f, 0.f, 0.f};
    float p1[4] = {0.f, 0.f, 0.f, 0.f};
    #pragma unroll
    for (int ot = 0; ot < 4; ++ot) {
        int col = ot * 16 + c;
        float bmc = bm1[col];
        float wc0 = Wm2[col * 2 + 0];
        float wc1 = Wm2[col * 2 + 1];
        f32x4 a = (ot == 0) ? acc0 : (ot == 1) ? acc1 : (ot == 2) ? acc2 : acc3;
        #pragma unroll
        for (int r = 0; r < 4; ++r) {
            float h = fmaxf(fmaf(rdr[r], a[r], bmc), 0.f);
            p0[r] = fmaf(h, wc0, p0[r]);
            p1[r] = fmaf(h, wc1, p1[r]);
        }
    }
    #pragma unroll
    for (int m = 1; m < 16; m <<= 1) {
        #pragma unroll
        for (int r = 0; r < 4; ++r) {
            p0[r] += __shfl_xor(p0[r], m);
            p1[r] += __shfl_xor(p1[r], m);
        }
    }
    if (c == 0) {
        float bo0 = bm2[0], bo1 = bm2[1];
        #pragma unroll
        for (int r = 0; r < 4; ++r) {
            int nd = nbase + qd * 4 + r;
            if (nd < N) {
                float2 o;
                o.x = p0[r] + bo0;
                o.y = p1[r] + bo1;
                *(float2*)(out + (size_t)nd * 2) = o;
            }
        }
    }
}

extern "C" void kernel_launch(void* const* d_in, const int* in_sizes, int n_in,
                              void* d_out, int out_size, void* d_ws, size_t ws_size,
                              hipStream_t stream) {
    const float* x   = (const float*)d_in[0];
    const int*   ei  = (const int*)d_in[1];
    const float* W1  = (const float*)d_in[2];
    const float* b1  = (const float*)d_in[3];
    const float* W2  = (const float*)d_in[4];
    const float* b2  = (const float*)d_in[5];
    const float* Wm1 = (const float*)d_in[6];
    const float* bm1 = (const float*)d_in[7];
    const float* Wm2 = (const float*)d_in[8];
    const float* bm2 = (const float*)d_in[9];
    float* out = (float*)d_out;

    int* ws = (int*)d_ws;
    int*   cnt   = ws + OFF_CNT;
    unsigned short* mpk = (unsigned short*)(ws + OFF_MPK);
    unsigned short* w1h = (unsigned short*)(ws + OFF_W1H);
    unsigned short* w1l = (unsigned short*)(ws + OFF_W1L);
    unsigned short* w2h = (unsigned short*)(ws + OFF_W2H);
    unsigned short* w2l = (unsigned short*)(ws + OFF_W2L);
    int*   offs  = ws + OFF_OFFS;
    float* d2a   = (float*)(ws + OFF_D2);
    float* rda   = (float*)(ws + OFF_RD);
    float* dinva = (float*)(ws + OFF_DINV);
    int*   adj   = ws + OFF_ADJ;
    unsigned short* gs0h = (unsigned short*)(ws + OFF_H0);
    unsigned short* gs1h = (unsigned short*)(ws + OFF_H1);
    unsigned short* gs2h = (unsigned short*)(ws + OFF_H2);
    int*   binned = ws + OFF_H1;   // aliases H1(+H2); dead before prop1 writes gs1h

    const int* srcp = ei;
    const int* dstp = ei + N_EDGES;

    k_prep<<<96, 256, 0, stream>>>(Wm1, W1, W2, mpk, w1h, w1l, w2h, w2l, cnt);
    k_bin<<<(N_EDGES + 2047) / 2048, 256, 0, stream>>>(srcp, dstp, cnt, binned, N_EDGES);
    k_cfill<<<NBKT, 256, 0, stream>>>(binned, cnt, offs, adj, d2a, rda, dinva);

    int nblk = (N_NODES + 63) / 64;
    k_gemm12<<<nblk, 256, 0, stream>>>(x, w1h, w1l, w2h, w2l, b1, b2, dinva, gs0h, N_NODES);

    k_prop<<<(N_NODES + 3) / 4, 256, 0, stream>>>(gs0h, gs1h, offs, adj, d2a, N_NODES);
    k_prop<<<(N_NODES + 3) / 4, 256, 0, stream>>>(gs1h, gs2h, offs, adj, d2a, N_NODES);

    k_final<<<nblk, 256, 0, stream>>>(gs0h, gs1h, gs2h, mpk, bm1, Wm2, bm2, rda, out, N_NODES);
}

// Round 11
// 248.801 us; speedup vs baseline: 1.6243x; 1.0216x over previous
//
#include <hip/hip_runtime.h>
#include <math.h>

#define N_NODES 100000
#define N_EDGES 1600000
#define IN_F 128
#define H_F 64

#define NBKT 391     // ceil(100000/256) buckets of 256 nodes
#define BSEG 5120    // per-bucket segment capacity (mean 4092, +16 sigma)
#define BCAP 5120    // LDS staging capacity for adj per bucket (20KB)

// workspace layout in 4-byte words (~46.5 MB total)
#define NP        100096
#define OFF_CNT   0                           // int[512]
#define OFF_MPK   512                         // ushort[12288] packed bf16 Mcat
#define OFF_W1H   6656                        // ushort[8192] W1 hi, B-frag order
#define OFF_W1L   10752                       // ushort[8192] W1 lo
#define OFF_W2H   14848                       // ushort[4096] W2 hi
#define OFF_W2L   16896                       // ushort[4096] W2 lo
#define OFF_OFFS  18944                       // int[N+1]
#define OFF_D2    (OFF_OFFS + NP + 64)        // float[NP]
#define OFF_RD    (OFF_D2 + NP)               // float[NP]
#define OFF_DINV  (OFF_RD + NP)               // float[NP]
#define OFF_ADJ   (OFF_DINV + NP)             // int[N_EDGES]
#define OFF_H0    (OFF_ADJ + N_EDGES)         // ushort[N*64] bf16 gs0
#define OFF_H1    (OFF_H0 + N_NODES*32)       // ushort[N*64] bf16 gs1; binned aliases H1+H2
#define OFF_H2    (OFF_H1 + N_NODES*32)       // ushort[N*64] bf16 gs2

typedef __attribute__((ext_vector_type(8))) short bf16x8;
typedef __attribute__((ext_vector_type(4))) float f32x4;

__device__ __forceinline__ unsigned short bf16rn(float f) {
    unsigned u = __float_as_uint(f);
    u += 0x7FFFu + ((u >> 16) & 1u);
    return (unsigned short)(u >> 16);
}
#define UNPK(u, lo, hi) { lo = __uint_as_float((u) << 16); hi = __uint_as_float((u) & 0xFFFF0000u); }
#define ACC8(v) { float l, h; \
    UNPK(v.x, l, h); a0 += l; a1 += h; \
    UNPK(v.y, l, h); a2 += l; a3 += h; \
    UNPK(v.z, l, h); a4 += l; a5 += h; \
    UNPK(v.w, l, h); a6 += l; a7 += h; }

// ---- prep: zero cnt; pack Mcat + split-bf16 W1/W2 B-fragments ----
__global__ __launch_bounds__(256) void k_prep(const float* __restrict__ Wm1,
        const float* __restrict__ W1, const float* __restrict__ W2,
        unsigned short* __restrict__ mpk,
        unsigned short* __restrict__ w1h, unsigned short* __restrict__ w1l,
        unsigned short* __restrict__ w2h, unsigned short* __restrict__ w2l,
        int* __restrict__ cnt) {
    int idx = blockIdx.x * 256 + threadIdx.x;
    if (idx < 512) cnt[idx] = 0;
    if (idx < 12288) {
        int j = idx & 7;
        int n = (idx >> 3) & 63;
        int qd = (idx >> 9) & 3;
        int s = idx >> 11;
        int k = s * 32 + qd * 8 + j;
        int p = k >> 6;
        int kk = k & 63;
        float w0 = Wm1[kk * 64 + n];
        float w1 = Wm1[(64 + kk) * 64 + n];
        float w2 = Wm1[(128 + kk) * 64 + n];
        float v;
        if (p == 0)      v = 3.0f * w0;
        else if (p == 1) v = 3.0f * (w1 - w0);
        else             v = 0.75f * (w0 + w2) - 1.5f * w1;
        mpk[idx] = bf16rn(v);
    } else if (idx < 12288 + 8192) {
        int lin = idx - 12288;
        int j = lin & 7, cc = (lin >> 3) & 15, ot = (lin >> 7) & 3;
        int qd = (lin >> 9) & 3, ks = lin >> 11;
        float v = W1[(ks * 32 + qd * 8 + j) * 64 + ot * 16 + cc];
        unsigned short h = bf16rn(v);
        w1h[lin] = h;
        w1l[lin] = bf16rn(v - __uint_as_float((unsigned)h << 16));
    } else if (idx < 24576) {
        int lin = idx - 20480;
        int j = lin & 7, cc = (lin >> 3) & 15, ot = (lin >> 7) & 3;
        int qd = (lin >> 9) & 3, ks = lin >> 11;
        float v = W2[(ks * 32 + qd * 8 + j) * 64 + ot * 16 + cc];
        unsigned short h = bf16rn(v);
        w2h[lin] = h;
        w2l[lin] = bf16rn(v - __uint_as_float((unsigned)h << 16));
    }
}

// ---- pass A: bin edges by dst>>8. 8192 edges/block so each bucket gets ~21
// contiguous entries per block -> whole-line writes (write amp ~1.3x).
__global__ __launch_bounds__(256) void k_bin(const int* __restrict__ src,
        const int* __restrict__ dst, int* __restrict__ cnt,
        int* __restrict__ binned, int E) {
    __shared__ int hist[4][NBKT + 1];
    __shared__ int cur4[4][NBKT + 1];
    int t = threadIdx.x;
    int w = t >> 6;
    for (int i = t; i < 4 * (NBKT + 1); i += 256) (&hist[0][0])[i] = 0;
    __syncthreads();
    int base = blockIdx.x * 8192 + t;
    int d[32];
    #pragma unroll
    for (int i = 0; i < 32; ++i) {
        int e = base + i * 256;
        int dd = (e < E) ? dst[e] : -1;
        d[i] = dd;
        if (dd >= 0) atomicAdd(&hist[w][dd >> 8], 1);
    }
    __syncthreads();
    for (int i = t; i < NBKT; i += 256) {
        int h0 = hist[0][i], h1 = hist[1][i], h2 = hist[2][i], h3 = hist[3][i];
        int tot = h0 + h1 + h2 + h3;
        int b0 = (tot > 0) ? atomicAdd(&cnt[i], tot) : 0;
        cur4[0][i] = b0;
        cur4[1][i] = b0 + h0;
        cur4[2][i] = b0 + h0 + h1;
        cur4[3][i] = b0 + h0 + h1 + h2;
    }
    __syncthreads();
    #pragma unroll
    for (int i = 0; i < 32; ++i) {
        int e = base + i * 256;
        if (e < E) {
            int s = src[e];
            int dd = d[i];
            int b = dd >> 8;
            int p = atomicAdd(&cur4[w][b], 1);
            if (p < BSEG) binned[b * BSEG + p] = ((dd & 255) << 17) | s;
        }
    }
}

// ---- pass B: per-bucket CSR fill (256 nodes/bucket) ----
__global__ __launch_bounds__(256) void k_cfill(const int* __restrict__ binned,
        const int* __restrict__ cnt, int* __restrict__ offs, int* __restrict__ adj,
        float* __restrict__ d2a, float* __restrict__ rda, float* __restrict__ dinva) {
    __shared__ int csum[256];
    __shared__ int degl[256];
    __shared__ int curl[256];
    __shared__ int wsum[4];
    __shared__ int adjl[BCAP];
    int b = blockIdx.x, t = threadIdx.x;
    int p = 0;
    if (2 * t < NBKT) p += cnt[2 * t];
    if (2 * t + 1 < NBKT) p += cnt[2 * t + 1];
    csum[t] = p;
    __syncthreads();
    #pragma unroll
    for (int off = 1; off < 256; off <<= 1) {
        int u = (t >= off) ? csum[t - off] : 0;
        __syncthreads();
        csum[t] += u;
        __syncthreads();
    }
    int b2 = b >> 1;
    int baseb = ((b2 > 0) ? csum[b2 - 1] : 0) + ((b & 1) ? cnt[b - 1] : 0);
    int cntb = cnt[b];
    if (b == 0 && t == 0) offs[N_NODES] = N_EDGES;
    int n0 = b << 8;
    const int* bp = binned + b * BSEG;
    degl[t] = 0;
    __syncthreads();
    for (int i = t; i < cntb; i += 256) atomicAdd(&degl[bp[i] >> 17], 1);
    __syncthreads();
    int d0 = degl[t];
    int lane = t & 63, wid = t >> 6;
    int inc = d0;
    #pragma unroll
    for (int off = 1; off < 64; off <<= 1) {
        int v = __shfl_up(inc, off, 64);
        if (lane >= off) inc += v;
    }
    if (lane == 63) wsum[wid] = inc;
    __syncthreads();
    int wb = 0;
    for (int w = 0; w < wid; ++w) wb += wsum[w];
    int excl = wb + inc - d0;
    curl[t] = excl;
    int n = n0 + t;
    if (n < N_NODES) {
        offs[n] = baseb + excl;
        float df = (float)d0;
        if (df < 1.f) df = 1.f;
        float di = 1.0f / sqrtf(df);
        dinva[n] = di;
        d2a[n] = di * di;
        rda[n] = sqrtf(df);
    }
    __syncthreads();
    for (int i = t; i < cntb; i += 256) {
        int w = bp[i];
        int loc = w >> 17;
        int s = w & 0x1FFFF;
        int pp = atomicAdd(&curl[loc], 1);
        if (pp < BCAP) adjl[pp] = s;
        else adj[baseb + pp] = s;
    }
    __syncthreads();
    int lim = cntb < BCAP ? cntb : BCAP;
    for (int i = t; i < lim; i += 256) adj[baseb + i] = adjl[i];
}

// ======= fused MLP via split-bf16 MFMA (fp32-accurate) ======================
__global__ __launch_bounds__(256) void k_gemm12(const float* __restrict__ x,
        const unsigned short* __restrict__ w1h, const unsigned short* __restrict__ w1l,
        const unsigned short* __restrict__ w2h, const unsigned short* __restrict__ w2l,
        const float* __restrict__ b1, const float* __restrict__ b2,
        const float* __restrict__ dinva, unsigned short* __restrict__ gsh, int N) {
    __shared__ unsigned int Hl[4][16 * 65];
    __shared__ unsigned short Sl[4][16 * 66];
    int t = threadIdx.x;
    int w = t >> 6, lane = t & 63;
    int c = lane & 15, qd = lane >> 4;
    int nbase = blockIdx.x * 64 + w * 16;
    if (nbase >= N) return;
    int node = nbase + c;
    int nclamp = (node < N) ? node : N - 1;

    f32x4 a0 = {0.f,0.f,0.f,0.f}, a1 = a0, a2 = a0, a3 = a0;
    #pragma unroll
    for (int ks = 0; ks < 4; ++ks) {
        const float* xp = x + (size_t)nclamp * IN_F + ks * 32 + qd * 8;
        float4 xa = *(const float4*)xp;
        float4 xb = *(const float4*)(xp + 4);
        float xs[8] = {xa.x, xa.y, xa.z, xa.w, xb.x, xb.y, xb.z, xb.w};
        bf16x8 ahi, alo;
        #pragma unroll
        for (int j = 0; j < 8; ++j) {
            unsigned short h = bf16rn(xs[j]);
            ahi[j] = (short)h;
            alo[j] = (short)bf16rn(xs[j] - __uint_as_float((unsigned)h << 16));
        }
        const unsigned short* bh = w1h + (size_t)(ks * 4 + qd) * 512;
        const unsigned short* bl = w1l + (size_t)(ks * 4 + qd) * 512;
        bf16x8 h0 = *(const bf16x8*)(bh + 0 * 128 + c * 8);
        bf16x8 l0 = *(const bf16x8*)(bl + 0 * 128 + c * 8);
        bf16x8 h1 = *(const bf16x8*)(bh + 1 * 128 + c * 8);
        bf16x8 l1 = *(const bf16x8*)(bl + 1 * 128 + c * 8);
        bf16x8 h2 = *(const bf16x8*)(bh + 2 * 128 + c * 8);
        bf16x8 l2 = *(const bf16x8*)(bl + 2 * 128 + c * 8);
        bf16x8 h3 = *(const bf16x8*)(bh + 3 * 128 + c * 8);
        bf16x8 l3 = *(const bf16x8*)(bl + 3 * 128 + c * 8);
        a0 = __builtin_amdgcn_mfma_f32_16x16x32_bf16(ahi, h0, a0, 0, 0, 0);
        a1 = __builtin_amdgcn_mfma_f32_16x16x32_bf16(ahi, h1, a1, 0, 0, 0);
        a2 = __builtin_amdgcn_mfma_f32_16x16x32_bf16(ahi, h2, a2, 0, 0, 0);
        a3 = __builtin_amdgcn_mfma_f32_16x16x32_bf16(ahi, h3, a3, 0, 0, 0);
        a0 = __builtin_amdgcn_mfma_f32_16x16x32_bf16(alo, h0, a0, 0, 0, 0);
        a1 = __builtin_amdgcn_mfma_f32_16x16x32_bf16(alo, h1, a1, 0, 0, 0);
        a2 = __builtin_amdgcn_mfma_f32_16x16x32_bf16(alo, h2, a2, 0, 0, 0);
        a3 = __builtin_amdgcn_mfma_f32_16x16x32_bf16(alo, h3, a3, 0, 0, 0);
        a0 = __builtin_amdgcn_mfma_f32_16x16x32_bf16(ahi, l0, a0, 0, 0, 0);
        a1 = __builtin_amdgcn_mfma_f32_16x16x32_bf16(ahi, l1, a1, 0, 0, 0);
        a2 = __builtin_amdgcn_mfma_f32_16x16x32_bf16(ahi, l2, a2, 0, 0, 0);
        a3 = __builtin_amdgcn_mfma_f32_16x16x32_bf16(ahi, l3, a3, 0, 0, 0);
    }
    #pragma unroll
    for (int ot = 0; ot < 4; ++ot) {
        float bb = b1[ot * 16 + c];
        f32x4 a = (ot == 0) ? a0 : (ot == 1) ? a1 : (ot == 2) ? a2 : a3;
        #pragma unroll
        for (int r = 0; r < 4; ++r) {
            float h = fmaxf(a[r] + bb, 0.f);
            unsigned short hh = bf16rn(h);
            unsigned short hl = bf16rn(h - __uint_as_float((unsigned)hh << 16));
            Hl[w][(qd * 4 + r) * 65 + ot * 16 + c] = ((unsigned)hh << 16) | hl;
        }
    }
    f32x4 d0 = {0.f,0.f,0.f,0.f}, d1 = d0, d2 = d0, d3 = d0;
    #pragma unroll
    for (int ks = 0; ks < 2; ++ks) {
        bf16x8 ahi, alo;
        #pragma unroll
        for (int j = 0; j < 8; ++j) {
            unsigned v = Hl[w][c * 65 + ks * 32 + qd * 8 + j];
            ahi[j] = (short)(v >> 16);
            alo[j] = (short)(v & 0xFFFFu);
        }
        const unsigned short* bh = w2h + (size_t)(ks * 4 + qd) * 512;
        const unsigned short* bl = w2l + (size_t)(ks * 4 + qd) * 512;
        bf16x8 h0 = *(const bf16x8*)(bh + 0 * 128 + c * 8);
        bf16x8 l0 = *(const bf16x8*)(bl + 0 * 128 + c * 8);
        bf16x8 h1 = *(const bf16x8*)(bh + 1 * 128 + c * 8);
        bf16x8 l1 = *(const bf16x8*)(bl + 1 * 128 + c * 8);
        bf16x8 h2 = *(const bf16x8*)(bh + 2 * 128 + c * 8);
        bf16x8 l2 = *(const bf16x8*)(bl + 2 * 128 + c * 8);
        bf16x8 h3 = *(const bf16x8*)(bh + 3 * 128 + c * 8);
        bf16x8 l3 = *(const bf16x8*)(bl + 3 * 128 + c * 8);
        d0 = __builtin_amdgcn_mfma_f32_16x16x32_bf16(ahi, h0, d0, 0, 0, 0);
        d1 = __builtin_amdgcn_mfma_f32_16x16x32_bf16(ahi, h1, d1, 0, 0, 0);
        d2 = __builtin_amdgcn_mfma_f32_16x16x32_bf16(ahi, h2, d2, 0, 0, 0);
        d3 = __builtin_amdgcn_mfma_f32_16x16x32_bf16(ahi, h3, d3, 0, 0, 0);
        d0 = __builtin_amdgcn_mfma_f32_16x16x32_bf16(alo, h0, d0, 0, 0, 0);
        d1 = __builtin_amdgcn_mfma_f32_16x16x32_bf16(alo, h1, d1, 0, 0, 0);
        d2 = __builtin_amdgcn_mfma_f32_16x16x32_bf16(alo, h2, d2, 0, 0, 0);
        d3 = __builtin_amdgcn_mfma_f32_16x16x32_bf16(alo, h3, d3, 0, 0, 0);
        d0 = __builtin_amdgcn_mfma_f32_16x16x32_bf16(ahi, l0, d0, 0, 0, 0);
        d1 = __builtin_amdgcn_mfma_f32_16x16x32_bf16(ahi, l1, d1, 0, 0, 0);
        d2 = __builtin_amdgcn_mfma_f32_16x16x32_bf16(ahi, l2, d2, 0, 0, 0);
        d3 = __builtin_amdgcn_mfma_f32_16x16x32_bf16(ahi, l3, d3, 0, 0, 0);
    }
    #pragma unroll
    for (int ot = 0; ot < 4; ++ot) {
        float bb = b2[ot * 16 + c];
        f32x4 a = (ot == 0) ? d0 : (ot == 1) ? d1 : (ot == 2) ? d2 : d3;
        #pragma unroll
        for (int r = 0; r < 4; ++r) {
            int nd = nbase + qd * 4 + r;
            float di = dinva[(nd < N) ? nd : N - 1];
            Sl[w][(qd * 4 + r) * 66 + ot * 16 + c] = bf16rn(di * fmaxf(a[r] + bb, 0.f));
        }
    }
    #pragma unroll
    for (int i = 0; i < 4; ++i) {
        int nl = i * 4 + qd;
        int nd = nbase + nl;
        if (nd < N) {
            ushort4 v;
            v.x = Sl[w][nl * 66 + c * 4 + 0];
            v.y = Sl[w][nl * 66 + c * 4 + 1];
            v.z = Sl[w][nl * 66 + c * 4 + 2];
            v.w = Sl[w][nl * 66 + c * 4 + 3];
            *(ushort4*)(gsh + (size_t)nd * 64 + c * 4) = v;
        }
    }
}

// ---- propagation (bf16 -> bf16), 2-ahead software pipeline ----
// 2 rows in flight per 8-lane group (16/wave) across the whole edge loop.
__global__ __launch_bounds__(256) void k_prop(const unsigned short* __restrict__ gh,
        unsigned short* __restrict__ gout, const int* __restrict__ offs,
        const int* __restrict__ adj, const float* __restrict__ d2a, int N) {
    int t = threadIdx.x;
    int lane = t & 63;
    int g = lane >> 3;
    int q = lane & 7;
    int n = blockIdx.x * 4 + (t >> 6);
    if (n >= N) return;
    int beg = offs[n], end = offs[n + 1];
    float d2n = d2a[n];                                        // early
    uint4 sv = *(const uint4*)(gh + (size_t)n * 64 + 8 * q);   // early self
    float a0 = 0.f, a1 = 0.f, a2 = 0.f, a3 = 0.f;
    float a4 = 0.f, a5 = 0.f, a6 = 0.f, a7 = 0.f;
    int e0 = beg + g;
    int e1 = e0 + 8;
    bool p0 = e0 < end;
    bool p1 = e1 < end;
    uint4 v0, v1;
    if (p0) v0 = *(const uint4*)(gh + (size_t)adj[e0] * 64 + 8 * q);
    if (p1) v1 = *(const uint4*)(gh + (size_t)adj[e1] * 64 + 8 * q);
    int e = e1 + 8;
    while (p1) {
        ACC8(v0);
        v0 = v1;
        p1 = e < end;
        if (p1) v1 = *(const uint4*)(gh + (size_t)adj[e] * 64 + 8 * q);
        e += 8;
    }
    if (p0) ACC8(v0);
    #pragma unroll
    for (int m = 8; m < 64; m <<= 1) {
        a0 += __shfl_xor(a0, m); a1 += __shfl_xor(a1, m);
        a2 += __shfl_xor(a2, m); a3 += __shfl_xor(a3, m);
        a4 += __shfl_xor(a4, m); a5 += __shfl_xor(a5, m);
        a6 += __shfl_xor(a6, m); a7 += __shfl_xor(a7, m);
    }
    if (g == 0) {
        float l, h;
        uint4 r;
        UNPK(sv.x, l, h);
        r.x = ((unsigned)bf16rn(fmaf(-d2n, a1, h)) << 16) | bf16rn(fmaf(-d2n, a0, l));
        UNPK(sv.y, l, h);
        r.y = ((unsigned)bf16rn(fmaf(-d2n, a3, h)) << 16) | bf16rn(fmaf(-d2n, a2, l));
        UNPK(sv.z, l, h);
        r.z = ((unsigned)bf16rn(fmaf(-d2n, a5, h)) << 16) | bf16rn(fmaf(-d2n, a4, l));
        UNPK(sv.w, l, h);
        r.w = ((unsigned)bf16rn(fmaf(-d2n, a7, h)) << 16) | bf16rn(fmaf(-d2n, a6, l));
        *(uint4*)(gout + (size_t)n * 64 + 8 * q) = r;
    }
}

// ---- MFMA head: wave = 16 nodes x 64 outs, K=192 over 3 bf16 slices ----
__global__ __launch_bounds__(256) void k_final(const unsigned short* __restrict__ g0h,
        const unsigned short* __restrict__ g1h, const unsigned short* __restrict__ g2h,
        const unsigned short* __restrict__ mpk, const float* __restrict__ bm1,
        const float* __restrict__ Wm2, const float* __restrict__ bm2,
        const float* __restrict__ rda, float* __restrict__ out, int N) {
    int t = threadIdx.x;
    int w = t >> 6, lane = t & 63;
    int c = lane & 15, qd = lane >> 4;
    int nbase = blockIdx.x * 64 + w * 16;
    if (nbase >= N) return;
    int node = nbase + c;
    int nclamp = (node < N) ? node : N - 1;
    const unsigned short* bufs[3] = {g0h, g1h, g2h};
    f32x4 acc0 = {0.f, 0.f, 0.f, 0.f};
    f32x4 acc1 = {0.f, 0.f, 0.f, 0.f};
    f32x4 acc2 = {0.f, 0.f, 0.f, 0.f};
    f32x4 acc3 = {0.f, 0.f, 0.f, 0.f};
    #pragma unroll
    for (int s = 0; s < 6; ++s) {
        const unsigned short* gp = bufs[s >> 1];
        int k0 = (s & 1) * 32;
        bf16x8 a = *(const bf16x8*)(gp + (size_t)nclamp * 64 + k0 + qd * 8);
        const unsigned short* mb = mpk + (size_t)((s * 4 + qd) * 64) * 8;
        bf16x8 b0 = *(const bf16x8*)(mb + (size_t)(c) * 8);
        bf16x8 b1 = *(const bf16x8*)(mb + (size_t)(16 + c) * 8);
        bf16x8 b2 = *(const bf16x8*)(mb + (size_t)(32 + c) * 8);
        bf16x8 b3 = *(const bf16x8*)(mb + (size_t)(48 + c) * 8);
        acc0 = __builtin_amdgcn_mfma_f32_16x16x32_bf16(a, b0, acc0, 0, 0, 0);
        acc1 = __builtin_amdgcn_mfma_f32_16x16x32_bf16(a, b1, acc1, 0, 0, 0);
        acc2 = __builtin_amdgcn_mfma_f32_16x16x32_bf16(a, b2, acc2, 0, 0, 0);
        acc3 = __builtin_amdgcn_mfma_f32_16x16x32_bf16(a, b3, acc3, 0, 0, 0);
    }
    float rdr[4];
    #pragma unroll
    for (int r = 0; r < 4; ++r) {
        int nd = nbase + qd * 4 + r;
        rdr[r] = rda[(nd < N) ? nd : N - 1];
    }
    float p0[4] = {0.f, 0.f, 0.f, 0.f};
    float p1[4] = {0.f, 0.f, 0.f, 0.f};
    #pragma unroll
    for (int ot = 0; ot < 4; ++ot) {
        int col = ot * 16 + c;
        float bmc = bm1[col];
        float wc0 = Wm2[col * 2 + 0];
        float wc1 = Wm2[col * 2 + 1];
        f32x4 a = (ot == 0) ? acc0 : (ot == 1) ? acc1 : (ot == 2) ? acc2 : acc3;
        #pragma unroll
        for (int r = 0; r < 4; ++r) {
            float h = fmaxf(fmaf(rdr[r], a[r], bmc), 0.f);
            p0[r] = fmaf(h, wc0, p0[r]);
            p1[r] = fmaf(h, wc1, p1[r]);
        }
    }
    #pragma unroll
    for (int m = 1; m < 16; m <<= 1) {
        #pragma unroll
        for (int r = 0; r < 4; ++r) {
            p0[r] += __shfl_xor(p0[r], m);
            p1[r] += __shfl_xor(p1[r], m);
        }
    }
    if (c == 0) {
        float bo0 = bm2[0], bo1 = bm2[1];
        #pragma unroll
        for (int r = 0; r < 4; ++r) {
            int nd = nbase + qd * 4 + r;
            if (nd < N) {
                float2 o;
                o.x = p0[r] + bo0;
                o.y = p1[r] + bo1;
                *(float2*)(out + (size_t)nd * 2) = o;
            }
        }
    }
}

extern "C" void kernel_launch(void* const* d_in, const int* in_sizes, int n_in,
                              void* d_out, int out_size, void* d_ws, size_t ws_size,
                              hipStream_t stream) {
    const float* x   = (const float*)d_in[0];
    const int*   ei  = (const int*)d_in[1];
    const float* W1  = (const float*)d_in[2];
    const float* b1  = (const float*)d_in[3];
    const float* W2  = (const float*)d_in[4];
    const float* b2  = (const float*)d_in[5];
    const float* Wm1 = (const float*)d_in[6];
    const float* bm1 = (const float*)d_in[7];
    const float* Wm2 = (const float*)d_in[8];
    const float* bm2 = (const float*)d_in[9];
    float* out = (float*)d_out;

    int* ws = (int*)d_ws;
    int*   cnt   = ws + OFF_CNT;
    unsigned short* mpk = (unsigned short*)(ws + OFF_MPK);
    unsigned short* w1h = (unsigned short*)(ws + OFF_W1H);
    unsigned short* w1l = (unsigned short*)(ws + OFF_W1L);
    unsigned short* w2h = (unsigned short*)(ws + OFF_W2H);
    unsigned short* w2l = (unsigned short*)(ws + OFF_W2L);
    int*   offs  = ws + OFF_OFFS;
    float* d2a   = (float*)(ws + OFF_D2);
    float* rda   = (float*)(ws + OFF_RD);
    float* dinva = (float*)(ws + OFF_DINV);
    int*   adj   = ws + OFF_ADJ;
    unsigned short* gs0h = (unsigned short*)(ws + OFF_H0);
    unsigned short* gs1h = (unsigned short*)(ws + OFF_H1);
    unsigned short* gs2h = (unsigned short*)(ws + OFF_H2);
    int*   binned = ws + OFF_H1;   // aliases H1(+H2); dead before prop1 writes gs1h

    const int* srcp = ei;
    const int* dstp = ei + N_EDGES;

    k_prep<<<96, 256, 0, stream>>>(Wm1, W1, W2, mpk, w1h, w1l, w2h, w2l, cnt);
    k_bin<<<(N_EDGES + 8191) / 8192, 256, 0, stream>>>(srcp, dstp, cnt, binned, N_EDGES);
    k_cfill<<<NBKT, 256, 0, stream>>>(binned, cnt, offs, adj, d2a, rda, dinva);

    int nblk = (N_NODES + 63) / 64;
    k_gemm12<<<nblk, 256, 0, stream>>>(x, w1h, w1l, w2h, w2l, b1, b2, dinva, gs0h, N_NODES);

    k_prop<<<(N_NODES + 3) / 4, 256, 0, stream>>>(gs0h, gs1h, offs, adj, d2a, N_NODES);
    k_prop<<<(N_NODES + 3) / 4, 256, 0, stream>>>(gs1h, gs2h, offs, adj, d2a, N_NODES);

    k_final<<<nblk, 256, 0, stream>>>(gs0h, gs1h, gs2h, mpk, bm1, Wm2, bm2, rda, out, N_NODES);
}